// Round 3
// baseline (2797.902 us; speedup 1.0000x reference)
//
#include <hip/hip_runtime.h>
#include <hip/hip_bf16.h>
#include <stdint.h>

// ---------------------------------------------------------------------------
// BiLSTM classifier: V=50000 E=100 H=128 B=128 T=1024 C=2. f32 I/O.
// Round 15 = swapped-operand MFMA lstm. Evidence (r13/r14): step time is
// serial-chain-latency bound (instr -20% gave 0; 4x write traffic gave +2%).
// mfma(wf, ah) -> D[m=gatecol][n=batchrow]: lane&15 = batch row, reg = col
// quad, so each lane owns 4 contiguous cols of ONE row -> the in-wave remap
// LDS roundtrip (~250 cyc on the chain) is gone, and the lane's 4col x 4gate
// xp quad is exactly the MFMA C operand -> xp add folds into C-init (unpack
// happens under the ds_read shadow). Blocks now carry 16 rows (16 blocks),
// all MFMA output rows valid. xpc layout [sl][row16][gate4][col128] bf16:
// proj waves write full 64B lines (fixes r14's 176MB partial-line writes).
// ---------------------------------------------------------------------------

typedef unsigned short u16;
typedef short bf16x8 __attribute__((ext_vector_type(8)));
typedef unsigned short ushort8v __attribute__((ext_vector_type(8)));
typedef float f32x4 __attribute__((ext_vector_type(4)));
typedef float f32x2 __attribute__((ext_vector_type(2)));
typedef unsigned int u32x2 __attribute__((ext_vector_type(2)));

#define NB 128
#define NT 1024
#define NH 128
#define TC 128         // chunk length (steps)
#define NCHUNK (NT / TC)

#define L2E  1.44269504088896f
#define L2E2 2.88539008177793f

__device__ __forceinline__ u16 f2bf(float f) {
  union { float f; unsigned int i; } v; v.f = f;
  unsigned int i = v.i;
  return (u16)((i + 0x7FFFu + ((i >> 16) & 1u)) >> 16);  // RNE
}

#if __has_builtin(__builtin_amdgcn_exp2f)
__device__ __forceinline__ float fast_exp2(float x) { return __builtin_amdgcn_exp2f(x); }
#else
__device__ __forceinline__ float fast_exp2(float x) { return exp2f(x); }
#endif
#if __has_builtin(__builtin_amdgcn_rcpf)
__device__ __forceinline__ float fast_rcp(float x) { return __builtin_amdgcn_rcpf(x); }
#else
__device__ __forceinline__ float fast_rcp(float x) { return 1.0f / x; }
#endif

// RNE f32x2 -> packed bf16 dword (low16 = lo, high16 = hi)
__device__ __forceinline__ unsigned int cvt_pk_bf16(float lo, float hi) {
  unsigned int r;
  asm("v_cvt_pk_bf16_f32 %0, %1, %2" : "=v"(r) : "v"(lo), "v"(hi));
  return r;
}

// unpack 4 bf16 (2 dwords) -> f32x4
__device__ __forceinline__ f32x4 xp_unpack(u32x2 d) {
  union { unsigned int u; float f; } a, b, c, e;
  a.u = d[0] << 16; b.u = d[0] & 0xFFFF0000u;
  c.u = d[1] << 16; e.u = d[1] & 0xFFFF0000u;
  return (f32x4){a.f, b.f, c.f, e.f};
}

// LDS-only waits: lgkmcnt(0), vmcnt/expcnt unconstrained (imm 0xc07f, gfx9).
__device__ __forceinline__ void sync_lds() {
  __builtin_amdgcn_s_waitcnt(0xc07f);
  __builtin_amdgcn_s_barrier();
}

// ---------------------------------------------------------------------------
// pad w_ih_l0 f32 [512,100] -> bf16 [2][512][128], rows scaled by gate factor
__global__ void padw_kernel(const float* __restrict__ w0, const float* __restrict__ w1,
                            u16* __restrict__ out) {
  int idx = blockIdx.x * 256 + threadIdx.x;  // 131072
  int d = idx >> 16;
  int n = (idx >> 7) & 511;
  int k = idx & 127;
  float sc = ((n >> 7) == 2) ? L2E2 : L2E;
  const float* w = d ? w1 : w0;
  out[idx] = (k < 100) ? f2bf(w[n * 100 + k] * sc) : (u16)0;
}

// fused f32->bf16 convert for 6 weight arrays, rows scaled by gate factor.
__global__ void cvt6_kernel(const float* s0, const float* s1, const float* s2,
                            const float* s3, const float* s4, const float* s5,
                            u16* d0, u16* d1, u16* d2, u16* d3, u16* d4, u16* d5,
                            int n0, int n1, int n2, int n3, int n4, int n5) {
  int y = blockIdx.y;
  const float* s; u16* d; int n; int gs;
  switch (y) {
    case 0: s = s0; d = d0; n = n0; gs = 14; break;
    case 1: s = s1; d = d1; n = n1; gs = 14; break;
    case 2: s = s2; d = d2; n = n2; gs = 14; break;
    case 3: s = s3; d = d3; n = n3; gs = 14; break;
    case 4: s = s4; d = d4; n = n4; gs = 15; break;
    default: s = s5; d = d5; n = n5; gs = 15; break;
  }
  int i = blockIdx.x * 256 + threadIdx.x;
  if (i < n) {
    float sc = (((i >> gs) & 3) == 2) ? L2E2 : L2E;
    d[i] = f2bf(s[i] * sc);
  }
}

// ---------------------------------------------------------------------------
// Fused kernel. Blocks 0..15: lstm chunk `lc` (16 batch rows each, 2 dirs x
// 8 wg). Blocks 16..1039: proj chunk `pc`.
// xpc layout: [dir*8+wg][sl][row16][gate4][col128] bf16 (16KB step tiles).
template <int PK, int LL>
__global__ __launch_bounds__(512) void fused_chunk(
    int do_lstm, int lc, int pc,
    const float* __restrict__ Aemb, const u16* __restrict__ Ah,
    const int* __restrict__ X,
    const u16* __restrict__ W0, const u16* __restrict__ W1,   // [512][PK] bf16
    const float* __restrict__ bih0, const float* __restrict__ bhh0,
    const float* __restrict__ bih1, const float* __restrict__ bhh1,
    u16* __restrict__ xpc0, u16* __restrict__ xpc1,           // double buffer
    const u16* __restrict__ WHH0, const u16* __restrict__ WHH1,
    u16* __restrict__ OUT, float* __restrict__ FINALS,
    u16* __restrict__ HS, float* __restrict__ CS)
{
  // smem: proj As(18432)+Bs(18432)+toks(512)=37376; lstm hb 2x16x152 u16=9728
  __shared__ __align__(16) unsigned char smem[37888];

  const int tid = threadIdx.x;
  const int lane = tid & 63, wv = tid >> 6;
  const int l15 = lane & 15, q = lane >> 4;

  if (blockIdx.x >= 16) {
    // ------------------------- proj part (8 waves, 64x32 wave tiles) -------
    constexpr int BK = 64;
    constexpr int LDA = 72;
    constexpr bool GATHER = (PK == 128);
    u16* As = (u16*)smem;
    u16* Bs = As + 128 * LDA;
    int* toks = (int*)(Bs + 128 * LDA);

    const int pb = blockIdx.x - 16;
    const int b = pb & 127;
    const int gate = (pb >> 7) & 3;
    const int nt0 = gate * 128;
    const int dir = pb >> 9;
    const u16* W = dir ? W1 : W0;
    u16* XPC = (pc & 1) ? xpc1 : xpc0;

    const int wr = wv >> 2, wc = wv & 3;   // 2 x 4 waves

    if (GATHER) {
      if (tid < 128) {
        int t = dir ? (NT - 1 - pc * TC - tid) : (pc * TC + tid);
        toks[tid] = X[b * NT + t];
      }
    }

    f32x4 acc[4][2];
#pragma unroll
    for (int a = 0; a < 4; a++)
#pragma unroll
      for (int bb = 0; bb < 2; bb++)
        acc[a][bb] = (f32x4){0.f, 0.f, 0.f, 0.f};

    const int srow = tid >> 3;        // 0..63
    const int sseg = (tid & 7) * 8;   // 0..56

    for (int k0 = 0; k0 < PK; k0 += BK) {
      __syncthreads();   // also covers toks on first iteration
#pragma unroll
      for (int p = 0; p < 2; p++) {
        int row = srow + p * 64;
        if (GATHER) {
          int tok = toks[row];
          const float* er = Aemb + (size_t)tok * 100;
          int kb = k0 + sseg;
          union { ushort8v v; u16 e[8]; } tu;
          if (kb + 8 <= 100) {
            f32x4 a0 = *(const f32x4*)&er[kb];
            f32x4 a1 = *(const f32x4*)&er[kb + 4];
#pragma unroll
            for (int j = 0; j < 4; j++) { tu.e[j] = f2bf(a0[j]); tu.e[4 + j] = f2bf(a1[j]); }
          } else {
#pragma unroll
            for (int j = 0; j < 8; j++) tu.e[j] = (kb + j < 100) ? f2bf(er[kb + j]) : (u16)0;
          }
          *(ushort8v*)&As[row * LDA + sseg] = tu.v;
        } else {
          int t = dir ? (NT - 1 - pc * TC - row) : (pc * TC + row);
          const u16* srcA = Ah + (size_t)(b * NT + t) * PK + k0 + sseg;
          *(ushort8v*)&As[row * LDA + sseg] = *(const ushort8v*)srcA;
        }
        const u16* srcB = W + (size_t)(nt0 + row) * PK + k0 + sseg;
        *(ushort8v*)&Bs[row * LDA + sseg] = *(const ushort8v*)srcB;
      }
      __syncthreads();
#pragma unroll
      for (int kk = 0; kk < BK; kk += 32) {
        bf16x8 af[4], bfr[2];
#pragma unroll
        for (int mt = 0; mt < 4; mt++)
          af[mt] = *(const bf16x8*)&As[(wr * 64 + mt * 16 + l15) * LDA + kk + q * 8];
#pragma unroll
        for (int nt = 0; nt < 2; nt++)
          bfr[nt] = *(const bf16x8*)&Bs[(wc * 32 + nt * 16 + l15) * LDA + kk + q * 8];
#pragma unroll
        for (int mt = 0; mt < 4; mt++)
#pragma unroll
          for (int nt = 0; nt < 2; nt++)
            acc[mt][nt] = __builtin_amdgcn_mfma_f32_16x16x32_bf16(af[mt], bfr[nt], acc[mt][nt], 0, 0, 0);
      }
    }

    const float* bih = dir ? bih1 : bih0;
    const float* bhh = dir ? bhh1 : bhh0;
    const float gsc = (gate == 2) ? L2E2 : L2E;
    // xpc: [dir*8 + b>>4][sl][row = b&15][gate][col]; per-wave full 64B lines
    u16* xo = XPC + (size_t)(dir * 8 + (b >> 4)) * TC * 8192
                  + (size_t)(b & 15) * 512 + gate * 128;
#pragma unroll
    for (int nt = 0; nt < 2; nt++) {
      int col = wc * 32 + nt * 16 + l15;          // within-gate col 0..127
      int n = nt0 + col;
      float bias = (bih[n] + bhh[n]) * gsc;
#pragma unroll
      for (int mt = 0; mt < 4; mt++) {
        int slb = wr * 64 + mt * 16 + q * 4;   // step-local index base
#pragma unroll
        for (int r = 0; r < 4; r++)
          xo[(size_t)(slb + r) * 8192 + col] = f2bf(acc[mt][nt][r] + bias);
      }
    }
    return;
  }

  // ------------------- lstm part (16 rows/WG, swapped MFMA, no remap) ------
  if (!do_lstm) return;

  __builtin_amdgcn_s_setprio(3);

  const int wg = blockIdx.x & 7, dir = blockIdx.x >> 3;   // 16 blocks
  const int hc = wv * 16 + l15;        // A-frag col (for wf load)
  const int cb = wv * 16 + (q << 2);   // this lane's 4-col base
  const u16* XPC = (lc & 1) ? xpc1 : xpc0;

  const u16* Wp = dir ? WHH1 : WHH0;
  bf16x8 wf[4][4];
#pragma unroll
  for (int gi = 0; gi < 4; gi++)
#pragma unroll
    for (int kt = 0; kt < 4; kt++)
      wf[gi][kt] = *(const bf16x8*)&Wp[(gi * 128 + hc) * 128 + kt * 32 + q * 8];

  u16* hb = (u16*)smem;   // [2][16][152] u16 (stride 152: 16B-aligned reads, 2-way banks)

  const int grow = (dir * 128 + wg * 16 + l15) * 128 + cb;  // HS/CS lane slot
  f32x4 cst4;
  if (lc == 0) {
    for (int i = tid; i < 2 * 16 * 152; i += 512) hb[i] = 0;
    cst4 = (f32x4){0.f, 0.f, 0.f, 0.f};
  } else {
    // each lane restores its own 4 cols of row l15 (plane 0 fully covered:
    // 512 lanes x 4 cols = 16 rows x 128 cols; plane 1 written in step 0)
    *(u32x2*)&hb[l15 * 152 + cb] = *(const u32x2*)&HS[grow];
    cst4 = *(const f32x4*)&CS[grow];
  }

  // xp lane base: row l15, gates 0..3 at col cb (4 bf16 = 8B per gate)
  const u16* xb = XPC + (size_t)(dir * 8 + wg) * TC * 8192 + l15 * 512 + cb;

  u32x2 xA[4], xB[4];
#pragma unroll
  for (int gi = 0; gi < 4; gi++)
    xA[gi] = *(const u32x2*)(xb + gi * 128);

  const int t0 = dir ? (NT - 1 - lc * TC) : (lc * TC);
  const int tstep = dir ? -256 : 256;
  u16* optr;
  if (LL == 0)
    optr = OUT + ((size_t)(wg * 16 + l15) * NT + t0) * 256 + dir * 128 + cb;

  __syncthreads();

  int p = 0;
#pragma unroll 1
  for (int sl = 0; sl < TC; sl += 2) {
#pragma unroll
    for (int half = 0; half < 2; half++) {
      const int scur = sl + half;
      u32x2* xcur = half ? xB : xA;
      u32x2* xnxt = half ? xA : xB;

      // B-fragment: h[row l15][k] from LDS (chain head after barrier)
      bf16x8 ah[4];
#pragma unroll
      for (int kt = 0; kt < 4; kt++)
        ah[kt] = *(const bf16x8*)&hb[p * 2432 + l15 * 152 + kt * 32 + q * 8];

      // prefetch next step's xp (off-chain; clamped re-read at chunk end)
      {
        const int sn = (scur + 1 < TC) ? scur + 1 : scur;
        const u16* nb = xb + (size_t)sn * 8192;
#pragma unroll
        for (int gi = 0; gi < 4; gi++)
          xnxt[gi] = *(const u32x2*)(nb + gi * 128);
      }

      // unpack xp -> C-init (runs under the ds_read latency shadow),
      // then swapped MFMA: D[m=col][n=row], lane owns row l15, cols cb..cb+3
      f32x4 acc[4];
#pragma unroll
      for (int gi = 0; gi < 4; gi++) {
        acc[gi] = xp_unpack(xcur[gi]);
#pragma unroll
        for (int kt = 0; kt < 4; kt++)
          acc[gi] = __builtin_amdgcn_mfma_f32_16x16x32_bf16(wf[gi][kt], ah[kt], acc[gi], 0, 0, 0);
      }

      // gate math, 4 cols wide (preacts pre-scaled by L2E/L2E2)
      f32x4 ei, ef, eg, eo;
#pragma unroll
      for (int r = 0; r < 4; r++) {
        ei[r] = fast_exp2(acc[0][r]);
        ef[r] = fast_exp2(acc[1][r]);
        eg[r] = fast_exp2(acc[2][r]);
        eo[r] = fast_exp2(acc[3][r]);
      }
      f32x4 A  = 1.f + ef;
      f32x4 Bv = 1.f + ei;
      f32x4 Cg = 1.f + eg;
      f32x4 BC = Bv * Cg;
      f32x4 num = cst4 * ef * BC + ei * (eg - 1.f) * A;
      f32x4 den = A * BC;
      f32x4 rden;
#pragma unroll
      for (int r = 0; r < 4; r++) rden[r] = fast_rcp(den[r]);
      f32x4 cn = num * rden;
      cst4 = cn;
      f32x4 ec;
#pragma unroll
      for (int r = 0; r < 4; r++) ec[r] = fast_exp2(L2E2 * cn[r]);
      f32x4 d2 = (1.f + eo) * (1.f + ec);
      f32x4 r2;
#pragma unroll
      for (int r = 0; r < 4; r++) r2[r] = fast_rcp(d2[r]);
      f32x4 hv = eo * (ec - 1.f) * r2;

      // pack 4 bf16 and write h (8B LDS write + 8B global store)
      u32x2 hw;
      hw[0] = cvt_pk_bf16(hv[0], hv[1]);
      hw[1] = cvt_pk_bf16(hv[2], hv[3]);
      *(u32x2*)&hb[(p ^ 1) * 2432 + l15 * 152 + cb] = hw;
      if (LL == 0) {
        *(u32x2*)optr = hw;
        optr += tstep;
      }
      if (scur == TC - 1) {
        *(u32x2*)&HS[grow] = hw;
        *(f32x4*)&CS[grow] = cst4;
        if (LL == 1 && lc == NCHUNK - 1)
          *(f32x4*)&FINALS[(wg * 16 + l15) * 256 + dir * 128 + cb] = hv;
      }
      sync_lds();   // h-exchange: lgkmcnt(0)+barrier; VMEM stays in flight
      p ^= 1;
    }
  }
}

// ---------------------------------------------------------------------------
// fc: out[b][c] = finals[b][:] . fc_w[c][:] + fc_b[c]  (all f32)
__global__ void fc_kernel(const float* __restrict__ finals, const float* __restrict__ fcw,
                          const float* __restrict__ fcb, float* __restrict__ out) {
  int tid = threadIdx.x;  // 256 = 128 b x 2 c
  int b = tid >> 1, cc = tid & 1;
  float s = fcb[cc];
  for (int k = 0; k < 256; k++) s += finals[b * 256 + k] * fcw[cc * 256 + k];
  out[b * 2 + cc] = s;
}

// ---------------------------------------------------------------------------
extern "C" void kernel_launch(void* const* d_in, const int* in_sizes, int n_in,
                              void* d_out, int out_size, void* d_ws, size_t ws_size,
                              hipStream_t stream) {
  const int*   x        = (const int*)d_in[0];
  const float* emb      = (const float*)d_in[1];
  const float* w_ih_l0  = (const float*)d_in[2];
  const float* w_hh_l0  = (const float*)d_in[3];
  const float* b_ih_l0  = (const float*)d_in[4];
  const float* b_hh_l0  = (const float*)d_in[5];
  const float* w_ih_l0r = (const float*)d_in[6];
  const float* w_hh_l0r = (const float*)d_in[7];
  const float* b_ih_l0r = (const float*)d_in[8];
  const float* b_hh_l0r = (const float*)d_in[9];
  const float* w_ih_l1  = (const float*)d_in[10];
  const float* w_hh_l1  = (const float*)d_in[11];
  const float* b_ih_l1  = (const float*)d_in[12];
  const float* b_hh_l1  = (const float*)d_in[13];
  const float* w_ih_l1r = (const float*)d_in[14];
  const float* w_hh_l1r = (const float*)d_in[15];
  const float* b_ih_l1r = (const float*)d_in[16];
  const float* b_hh_l1r = (const float*)d_in[17];
  const float* fc_w     = (const float*)d_in[18];
  const float* fc_b     = (const float*)d_in[19];
  float* out = (float*)d_out;

  // workspace layout — total 135,856,128 B (r8-r14 footprint, proven)
  char* ws = (char*)d_ws;
  size_t off = 0;
  u16*   h1cat = (u16*)(ws + off);   off += 67108864;  // [NB*NT][256] bf16
  u16*   xpc0  = (u16*)(ws + off);   off += 33554432;  // xp double buffer 0
  u16*   xpc1  = (u16*)(ws + off);   off += 33554432;  // xp double buffer 1
  u16*   w0pad = (u16*)(ws + off);   off += 262144;    // [2][512][128] bf16 (scaled)
  u16*   wih1b = (u16*)(ws + off);   off += 524288;    // [2][512][256] bf16 (scaled)
  u16*   whhb  = (u16*)(ws + off);   off += 524288;    // [4][512][128] bf16 (scaled)
  u16*   hs    = (u16*)(ws + off);   off += 65536;     // [2][128][128] bf16
  float* cs    = (float*)(ws + off); off += 131072;    // [2][128][128] f32
  float* fin   = (float*)(ws + off); off += 131072;    // [128][256] f32
  if (ws_size < off) return;  // constant across calls -> same work every call

  hipLaunchKernelGGL(padw_kernel, dim3(512), dim3(256), 0, stream,
                     w_ih_l0, w_ih_l0r, w0pad);
  hipLaunchKernelGGL(cvt6_kernel, dim3(512, 6), dim3(256), 0, stream,
                     w_hh_l0, w_hh_l0r, w_hh_l1, w_hh_l1r, w_ih_l1, w_ih_l1r,
                     whhb, whhb + 65536, whhb + 131072, whhb + 196608,
                     wih1b, wih1b + 131072,
                     65536, 65536, 65536, 65536, 131072, 131072);

  // Layer 0: launch k does proj0(k) [k<8] fused with lstm0(k-1) [k>0]
  for (int k = 0; k <= NCHUNK; k++) {
    int do_proj = (k < NCHUNK);
    int do_lstm = (k > 0);
    hipLaunchKernelGGL((fused_chunk<128, 0>), dim3(do_proj ? 1040 : 16), dim3(512), 0, stream,
                       do_lstm, k - 1, k,
                       emb, (const u16*)nullptr, x, w0pad, w0pad + 65536,
                       b_ih_l0, b_hh_l0, b_ih_l0r, b_hh_l0r,
                       xpc0, xpc1, whhb, whhb + 65536,
                       h1cat, fin, hs, cs);
  }
  // Layer 1: same pattern, proj reads h1cat (complete after layer-0 phase)
  for (int k = 0; k <= NCHUNK; k++) {
    int do_proj = (k < NCHUNK);
    int do_lstm = (k > 0);
    hipLaunchKernelGGL((fused_chunk<256, 1>), dim3(do_proj ? 1040 : 16), dim3(512), 0, stream,
                       do_lstm, k - 1, k,
                       (const float*)nullptr, h1cat, (const int*)nullptr,
                       wih1b, wih1b + 131072,
                       b_ih_l1, b_hh_l1, b_ih_l1r, b_hh_l1r,
                       xpc0, xpc1, whhb + 131072, whhb + 196608,
                       h1cat, fin, hs, cs);
  }
  hipLaunchKernelGGL(fc_kernel, dim3(1), dim3(256), 0, stream, fin, fc_w, fc_b, out);
}

// Round 4
// 1867.238 us; speedup vs baseline: 1.4984x; 1.4984x over previous
//
#include <hip/hip_runtime.h>
#include <hip/hip_bf16.h>
#include <stdint.h>

// ---------------------------------------------------------------------------
// BiLSTM classifier: V=50000 E=100 H=128 B=128 T=1024 C=2. f32 I/O.
// Round 16 = r13 structure (proven 118.8us/dispatch: 32 lstm blocks, 8 rows,
// in-wave remap, packed-f32x2 gates) + DEPTH-2 xp prefetch. Theory: the
// ~2230cyc/step constant (instr-count-invariant, setprio-invariant) is a
// vmcnt stall on xp loads: xpc is L2-thrashed by concurrent proj traffic ->
// ~900cyc+ HBM latency, and r13 prefetched only 1 step (~1100cyc) ahead.
// Depth-2 (use-to-load distance ~2 steps) takes the stall off the chain.
// xpc layout [tile][sl][rowpair4][gate4][col128][par2]: lane's 2 rows x 1
// gate are adjacent u16 -> 4 dword loads/step; proj store partner (par bit)
// is adjacent blockIdx -> L2 line merge (bounded write inflation <=2x).
// ---------------------------------------------------------------------------

typedef unsigned short u16;
typedef short bf16x8 __attribute__((ext_vector_type(8)));
typedef unsigned short ushort8v __attribute__((ext_vector_type(8)));
typedef float f32x4 __attribute__((ext_vector_type(4)));
typedef float f32x2 __attribute__((ext_vector_type(2)));

#define NB 128
#define NT 1024
#define NH 128
#define TC 128         // chunk length (steps)
#define NCHUNK (NT / TC)

#define L2E  1.44269504088896f
#define L2E2 2.88539008177793f

__device__ __forceinline__ u16 f2bf(float f) {
  union { float f; unsigned int i; } v; v.f = f;
  unsigned int i = v.i;
  return (u16)((i + 0x7FFFu + ((i >> 16) & 1u)) >> 16);  // RNE
}

#if __has_builtin(__builtin_amdgcn_exp2f)
__device__ __forceinline__ float fast_exp2(float x) { return __builtin_amdgcn_exp2f(x); }
#else
__device__ __forceinline__ float fast_exp2(float x) { return exp2f(x); }
#endif
#if __has_builtin(__builtin_amdgcn_rcpf)
__device__ __forceinline__ float fast_rcp(float x) { return __builtin_amdgcn_rcpf(x); }
#else
__device__ __forceinline__ float fast_rcp(float x) { return 1.0f / x; }
#endif

// LDS-only waits: lgkmcnt(0), vmcnt/expcnt unconstrained (imm 0xc07f, gfx9).
__device__ __forceinline__ void wait_lds() { __builtin_amdgcn_s_waitcnt(0xc07f); }
__device__ __forceinline__ void sync_lds() {
  __builtin_amdgcn_s_waitcnt(0xc07f);
  __builtin_amdgcn_s_barrier();
}

// ---------------------------------------------------------------------------
// pad w_ih_l0 f32 [512,100] -> bf16 [2][512][128], rows scaled by gate factor
__global__ void padw_kernel(const float* __restrict__ w0, const float* __restrict__ w1,
                            u16* __restrict__ out) {
  int idx = blockIdx.x * 256 + threadIdx.x;  // 131072
  int d = idx >> 16;
  int n = (idx >> 7) & 511;
  int k = idx & 127;
  float sc = ((n >> 7) == 2) ? L2E2 : L2E;
  const float* w = d ? w1 : w0;
  out[idx] = (k < 100) ? f2bf(w[n * 100 + k] * sc) : (u16)0;
}

// fused f32->bf16 convert for 6 weight arrays, rows scaled by gate factor.
__global__ void cvt6_kernel(const float* s0, const float* s1, const float* s2,
                            const float* s3, const float* s4, const float* s5,
                            u16* d0, u16* d1, u16* d2, u16* d3, u16* d4, u16* d5,
                            int n0, int n1, int n2, int n3, int n4, int n5) {
  int y = blockIdx.y;
  const float* s; u16* d; int n; int gs;
  switch (y) {
    case 0: s = s0; d = d0; n = n0; gs = 14; break;
    case 1: s = s1; d = d1; n = n1; gs = 14; break;
    case 2: s = s2; d = d2; n = n2; gs = 14; break;
    case 3: s = s3; d = d3; n = n3; gs = 14; break;
    case 4: s = s4; d = d4; n = n4; gs = 15; break;
    default: s = s5; d = d5; n = n5; gs = 15; break;
  }
  int i = blockIdx.x * 256 + threadIdx.x;
  if (i < n) {
    float sc = (((i >> gs) & 3) == 2) ? L2E2 : L2E;
    d[i] = f2bf(s[i] * sc);
  }
}

// ---------------------------------------------------------------------------
// Fused kernel. Blocks 0..31: lstm chunk `lc` (8 batch rows each, 2 dirs x
// 16 wg). Blocks 32..1055: proj chunk `pc`.
// xpc layout: [dir*16+wg][sl][rowpair4][gate4][col128][par2] u16
//             (8KB step tiles; one dword per lane per gate per step).
template <int PK, int LL>
__global__ __launch_bounds__(512) void fused_chunk(
    int do_lstm, int lc, int pc,
    const float* __restrict__ Aemb, const u16* __restrict__ Ah,
    const int* __restrict__ X,
    const u16* __restrict__ W0, const u16* __restrict__ W1,   // [512][PK] bf16
    const float* __restrict__ bih0, const float* __restrict__ bhh0,
    const float* __restrict__ bih1, const float* __restrict__ bhh1,
    u16* __restrict__ xpc0, u16* __restrict__ xpc1,           // double buffer
    const u16* __restrict__ WHH0, const u16* __restrict__ WHH1,
    u16* __restrict__ OUT, float* __restrict__ FINALS,
    u16* __restrict__ HS, float* __restrict__ CS)
{
  // smem: proj As(18432)+Bs(18432)+toks(512)=37376; lstm hb(8704)+remap(16K)
  __shared__ __align__(16) unsigned char smem[37888];

  const int tid = threadIdx.x;
  const int lane = tid & 63, wv = tid >> 6;
  const int l15 = lane & 15, q = lane >> 4;

  if (blockIdx.x >= 32) {
    // ------------------------- proj part (8 waves, 64x32 wave tiles) -------
    constexpr int BK = 64;
    constexpr int LDA = 72;
    constexpr bool GATHER = (PK == 128);
    u16* As = (u16*)smem;
    u16* Bs = As + 128 * LDA;
    int* toks = (int*)(Bs + 128 * LDA);

    const int pb = blockIdx.x - 32;
    const int b = pb & 127;
    const int gate = (pb >> 7) & 3;
    const int nt0 = gate * 128;
    const int dir = pb >> 9;
    const u16* W = dir ? W1 : W0;
    u16* XPC = (pc & 1) ? xpc1 : xpc0;

    const int wr = wv >> 2, wc = wv & 3;   // 2 x 4 waves

    if (GATHER) {
      if (tid < 128) {
        int t = dir ? (NT - 1 - pc * TC - tid) : (pc * TC + tid);
        toks[tid] = X[b * NT + t];
      }
    }

    f32x4 acc[4][2];
#pragma unroll
    for (int a = 0; a < 4; a++)
#pragma unroll
      for (int bb = 0; bb < 2; bb++)
        acc[a][bb] = (f32x4){0.f, 0.f, 0.f, 0.f};

    const int srow = tid >> 3;        // 0..63
    const int sseg = (tid & 7) * 8;   // 0..56

    for (int k0 = 0; k0 < PK; k0 += BK) {
      __syncthreads();   // also covers toks on first iteration
#pragma unroll
      for (int p = 0; p < 2; p++) {
        int row = srow + p * 64;
        if (GATHER) {
          int tok = toks[row];
          const float* er = Aemb + (size_t)tok * 100;
          int kb = k0 + sseg;
          union { ushort8v v; u16 e[8]; } tu;
          if (kb + 8 <= 100) {
            f32x4 a0 = *(const f32x4*)&er[kb];
            f32x4 a1 = *(const f32x4*)&er[kb + 4];
#pragma unroll
            for (int j = 0; j < 4; j++) { tu.e[j] = f2bf(a0[j]); tu.e[4 + j] = f2bf(a1[j]); }
          } else {
#pragma unroll
            for (int j = 0; j < 8; j++) tu.e[j] = (kb + j < 100) ? f2bf(er[kb + j]) : (u16)0;
          }
          *(ushort8v*)&As[row * LDA + sseg] = tu.v;
        } else {
          int t = dir ? (NT - 1 - pc * TC - row) : (pc * TC + row);
          const u16* srcA = Ah + (size_t)(b * NT + t) * PK + k0 + sseg;
          *(ushort8v*)&As[row * LDA + sseg] = *(const ushort8v*)srcA;
        }
        const u16* srcB = W + (size_t)(nt0 + row) * PK + k0 + sseg;
        *(ushort8v*)&Bs[row * LDA + sseg] = *(const ushort8v*)srcB;
      }
      __syncthreads();
#pragma unroll
      for (int kk = 0; kk < BK; kk += 32) {
        bf16x8 af[4], bfr[2];
#pragma unroll
        for (int mt = 0; mt < 4; mt++)
          af[mt] = *(const bf16x8*)&As[(wr * 64 + mt * 16 + l15) * LDA + kk + q * 8];
#pragma unroll
        for (int nt = 0; nt < 2; nt++)
          bfr[nt] = *(const bf16x8*)&Bs[(wc * 32 + nt * 16 + l15) * LDA + kk + q * 8];
#pragma unroll
        for (int mt = 0; mt < 4; mt++)
#pragma unroll
          for (int nt = 0; nt < 2; nt++)
            acc[mt][nt] = __builtin_amdgcn_mfma_f32_16x16x32_bf16(af[mt], bfr[nt], acc[mt][nt], 0, 0, 0);
      }
    }

    const float* bih = dir ? bih1 : bih0;
    const float* bhh = dir ? bhh1 : bhh0;
    const float gsc = (gate == 2) ? L2E2 : L2E;
    // xpc: [dir*16 + b>>3][sl][rowpair = (b&7)>>1][gate][col][par = b&1]
    const int rb = b & 7;
    u16* xo = XPC + (size_t)(dir * 16 + (b >> 3)) * TC * 4096
                  + (size_t)(rb >> 1) * 1024 + gate * 256 + (rb & 1);
#pragma unroll
    for (int nt = 0; nt < 2; nt++) {
      int col = wc * 32 + nt * 16 + l15;          // within-gate col 0..127
      int n = nt0 + col;
      float bias = (bih[n] + bhh[n]) * gsc;
#pragma unroll
      for (int mt = 0; mt < 4; mt++) {
        int slb = wr * 64 + mt * 16 + q * 4;   // step-local index base
#pragma unroll
        for (int r = 0; r < 4; r++)
          xo[(size_t)(slb + r) * 4096 + col * 2] = f2bf(acc[mt][nt][r] + bias);
      }
    }
    return;
  }

  // --------------------------- lstm part (8 rows/WG + in-wave remap) -------
  if (!do_lstm) return;

  __builtin_amdgcn_s_setprio(3);

  const int wg = blockIdx.x & 15, dir = blockIdx.x >> 4;
  const int hc = 16 * wv + l15;
  const u16* XPC = (lc & 1) ? xpc1 : xpc0;

  const u16* Wp = dir ? WHH1 : WHH0;
  bf16x8 wf[4][4];
#pragma unroll
  for (int gi = 0; gi < 4; gi++)
#pragma unroll
    for (int kt = 0; kt < 4; kt++)
      wf[gi][kt] = *(const bf16x8*)&Wp[(gi * 128 + hc) * 128 + kt * 32 + q * 8];

  u16* hb = (u16*)smem;                               // [2][16*136] u16
  float* wsc = (float*)(smem + 8704 + wv * 2048);     // per-wave remap scratch

  f32x2 cst2;
  if (lc == 0) {
    for (int i = tid; i < 2 * 16 * 136; i += 512) hb[i] = 0;
    cst2 = (f32x2){0.f, 0.f};
  } else {
    // zero rows 8..15 of both planes (MFMA garbage guard)
    for (int i = tid; i < 2 * 8 * 136; i += 512) {
      int pl = i / (8 * 136), j = i - pl * (8 * 136);
      hb[pl * 2176 + 8 * 136 + j] = 0;
    }
    // load rows 0..7 (this lane owns rows 2q, 2q+1 at col hc)
#pragma unroll
    for (int rr = 0; rr < 2; rr++) {
      int row = 2 * q + rr;
      int g = (dir * 128 + wg * 8 + row) * 128 + hc;
      hb[row * 136 + hc] = HS[g];
      cst2[rr] = CS[g];
    }
  }

  // xp lane base: rowpair q, col hc -> one dword per gate per step.
  // u16 offset within step tile: q*1024 + gi*256 + hc*2; step stride 4096.
  const u16* xb = XPC + (size_t)(dir * 16 + wg) * TC * 4096 + q * 1024 + hc * 2;

#define LDXP(dst, s) do {                                        \
    const u16* nb_ = xb + (size_t)(s) * 4096;                    \
    _Pragma("unroll")                                            \
    for (int gi_ = 0; gi_ < 4; gi_++)                            \
      (dst)[gi_] = *(const unsigned int*)(nb_ + gi_ * 256);      \
  } while (0)

  // depth-2 prefetch: 4 rotating dword[4] buffers, static indexing
  unsigned int xp[4][4];
  LDXP(xp[0], 0);
  LDXP(xp[1], 1);

  const int t0 = dir ? (NT - 1 - lc * TC) : (lc * TC);
  const int tstep = dir ? -256 : 256;
  u16* optr[2];
  if (LL == 0) {
#pragma unroll
    for (int rr = 0; rr < 2; rr++)
      optr[rr] = OUT + ((size_t)(wg * 8 + 2 * q + rr) * NT + t0) * 256 + dir * 128 + hc;
  }

  const f32x4 zero4 = {0.f, 0.f, 0.f, 0.f};

  __syncthreads();

  int p = 0;
#pragma unroll 1
  for (int sl = 0; sl < TC; sl += 4) {
#pragma unroll
    for (int jj = 0; jj < 4; jj++) {
      const int scur = sl + jj;
      const unsigned int* xcur = xp[jj];
      unsigned int* xnxt = xp[(jj + 2) & 3];

      bf16x8 ah[4];
#pragma unroll
      for (int kt = 0; kt < 4; kt++)
        ah[kt] = *(const bf16x8*)&hb[p * 2176 + l15 * 136 + kt * 32 + q * 8];

      // prefetch step scur+2 (clamped: harmless re-read near chunk end)
      {
        int sn = scur + 2; if (sn > TC - 1) sn = TC - 1;
        LDXP(xnxt, sn);
      }

      // MFMA with zero C-init (xp added after remap)
      f32x4 acc[4];
#pragma unroll
      for (int gi = 0; gi < 4; gi++) {
        acc[gi] = __builtin_amdgcn_mfma_f32_16x16x32_bf16(ah[0], wf[gi][0], zero4, 0, 0, 0);
#pragma unroll
        for (int kt = 1; kt < 4; kt++)
          acc[gi] = __builtin_amdgcn_mfma_f32_16x16x32_bf16(ah[kt], wf[gi][kt], acc[gi], 0, 0, 0);
      }

      // in-wave remap: valid rows live in lanes q<2 (C rows q*4+r < 8);
      // scratch layout [gi][col l15][row 0..7] f32 -> each lane picks up
      // rows {2q, 2q+1} at its col. Wave-internal: lgkm wait, no barrier.
      if (lane < 32) {
#pragma unroll
        for (int gi = 0; gi < 4; gi++)
          *(f32x4*)&wsc[gi * 128 + l15 * 8 + (lane >> 4) * 4] = acc[gi];
      }
      wait_lds();
      f32x2 ar[4];
#pragma unroll
      for (int gi = 0; gi < 4; gi++)
        ar[gi] = *(const f32x2*)&wsc[gi * 128 + l15 * 8 + q * 2];

      // unpack xp dwords -> f32x2 over rr (par0 -> <<16, par1 -> mask)
      f32x2 xv[4];
#pragma unroll
      for (int gi = 0; gi < 4; gi++) {
        union { unsigned int u; float f; } lo, hi;
        lo.u = xcur[gi] << 16;
        hi.u = xcur[gi] & 0xFFFF0000u;
        xv[gi][0] = lo.f; xv[gi][1] = hi.f;
      }

      // packed gate math (rr = vector lane). Preacts pre-scaled by L2E/L2E2.
      f32x2 pi = ar[0] + xv[0];
      f32x2 pf = ar[1] + xv[1];
      f32x2 pg = ar[2] + xv[2];
      f32x2 po = ar[3] + xv[3];
      f32x2 ei, ef, eg, eo;
      ei[0] = fast_exp2(pi[0]); ei[1] = fast_exp2(pi[1]);
      ef[0] = fast_exp2(pf[0]); ef[1] = fast_exp2(pf[1]);
      eg[0] = fast_exp2(pg[0]); eg[1] = fast_exp2(pg[1]);
      eo[0] = fast_exp2(po[0]); eo[1] = fast_exp2(po[1]);
      f32x2 A  = 1.f + ef;
      f32x2 Bv = 1.f + ei;
      f32x2 Cg = 1.f + eg;
      f32x2 BC = Bv * Cg;
      f32x2 num = cst2 * ef * BC + ei * (eg - 1.f) * A;
      f32x2 den = A * BC;
      f32x2 rden; rden[0] = fast_rcp(den[0]); rden[1] = fast_rcp(den[1]);
      f32x2 cn = num * rden;
      cst2 = cn;
      f32x2 tc2 = L2E2 * cn;
      f32x2 ec; ec[0] = fast_exp2(tc2[0]); ec[1] = fast_exp2(tc2[1]);
      f32x2 d2 = (1.f + eo) * (1.f + ec);
      f32x2 r2; r2[0] = fast_rcp(d2[0]); r2[1] = fast_rcp(d2[1]);
      f32x2 hv2 = eo * (ec - 1.f) * r2;

#pragma unroll
      for (int rr = 0; rr < 2; rr++) {
        u16 hbv = f2bf(hv2[rr]);
        int row = 2 * q + rr;
        hb[(p ^ 1) * 2176 + row * 136 + hc] = hbv;
        if (LL == 0) {
          *optr[rr] = hbv;
          optr[rr] += tstep;
        }
        if (scur == TC - 1) {
          int g = (dir * 128 + wg * 8 + row) * 128 + hc;
          HS[g] = hbv;
          CS[g] = cst2[rr];
          if (LL == 1 && lc == NCHUNK - 1)
            FINALS[(wg * 8 + row) * 256 + dir * 128 + hc] = hv2[rr];
        }
      }
      sync_lds();   // h-exchange: lgkmcnt(0)+barrier; VMEM stays in flight
      p ^= 1;
    }
  }
#undef LDXP
}

// ---------------------------------------------------------------------------
// fc: out[b][c] = finals[b][:] . fc_w[c][:] + fc_b[c]  (all f32)
__global__ void fc_kernel(const float* __restrict__ finals, const float* __restrict__ fcw,
                          const float* __restrict__ fcb, float* __restrict__ out) {
  int tid = threadIdx.x;  // 256 = 128 b x 2 c
  int b = tid >> 1, cc = tid & 1;
  float s = fcb[cc];
  for (int k = 0; k < 256; k++) s += finals[b * 256 + k] * fcw[cc * 256 + k];
  out[b * 2 + cc] = s;
}

// ---------------------------------------------------------------------------
extern "C" void kernel_launch(void* const* d_in, const int* in_sizes, int n_in,
                              void* d_out, int out_size, void* d_ws, size_t ws_size,
                              hipStream_t stream) {
  const int*   x        = (const int*)d_in[0];
  const float* emb      = (const float*)d_in[1];
  const float* w_ih_l0  = (const float*)d_in[2];
  const float* w_hh_l0  = (const float*)d_in[3];
  const float* b_ih_l0  = (const float*)d_in[4];
  const float* b_hh_l0  = (const float*)d_in[5];
  const float* w_ih_l0r = (const float*)d_in[6];
  const float* w_hh_l0r = (const float*)d_in[7];
  const float* b_ih_l0r = (const float*)d_in[8];
  const float* b_hh_l0r = (const float*)d_in[9];
  const float* w_ih_l1  = (const float*)d_in[10];
  const float* w_hh_l1  = (const float*)d_in[11];
  const float* b_ih_l1  = (const float*)d_in[12];
  const float* b_hh_l1  = (const float*)d_in[13];
  const float* w_ih_l1r = (const float*)d_in[14];
  const float* w_hh_l1r = (const float*)d_in[15];
  const float* b_ih_l1r = (const float*)d_in[16];
  const float* b_hh_l1r = (const float*)d_in[17];
  const float* fc_w     = (const float*)d_in[18];
  const float* fc_b     = (const float*)d_in[19];
  float* out = (float*)d_out;

  // workspace layout — total 135,856,128 B (r8-r14 footprint, proven)
  char* ws = (char*)d_ws;
  size_t off = 0;
  u16*   h1cat = (u16*)(ws + off);   off += 67108864;  // [NB*NT][256] bf16
  u16*   xpc0  = (u16*)(ws + off);   off += 33554432;  // xp double buffer 0
  u16*   xpc1  = (u16*)(ws + off);   off += 33554432;  // xp double buffer 1
  u16*   w0pad = (u16*)(ws + off);   off += 262144;    // [2][512][128] bf16 (scaled)
  u16*   wih1b = (u16*)(ws + off);   off += 524288;    // [2][512][256] bf16 (scaled)
  u16*   whhb  = (u16*)(ws + off);   off += 524288;    // [4][512][128] bf16 (scaled)
  u16*   hs    = (u16*)(ws + off);   off += 65536;     // [2][128][128] bf16
  float* cs    = (float*)(ws + off); off += 131072;    // [2][128][128] f32
  float* fin   = (float*)(ws + off); off += 131072;    // [128][256] f32
  if (ws_size < off) return;  // constant across calls -> same work every call

  hipLaunchKernelGGL(padw_kernel, dim3(512), dim3(256), 0, stream,
                     w_ih_l0, w_ih_l0r, w0pad);
  hipLaunchKernelGGL(cvt6_kernel, dim3(512, 6), dim3(256), 0, stream,
                     w_hh_l0, w_hh_l0r, w_hh_l1, w_hh_l1r, w_ih_l1, w_ih_l1r,
                     whhb, whhb + 65536, whhb + 131072, whhb + 196608,
                     wih1b, wih1b + 131072,
                     65536, 65536, 65536, 65536, 131072, 131072);

  // Layer 0: launch k does proj0(k) [k<8] fused with lstm0(k-1) [k>0]
  for (int k = 0; k <= NCHUNK; k++) {
    int do_proj = (k < NCHUNK);
    int do_lstm = (k > 0);
    hipLaunchKernelGGL((fused_chunk<128, 0>), dim3(do_proj ? 1056 : 32), dim3(512), 0, stream,
                       do_lstm, k - 1, k,
                       emb, (const u16*)nullptr, x, w0pad, w0pad + 65536,
                       b_ih_l0, b_hh_l0, b_ih_l0r, b_hh_l0r,
                       xpc0, xpc1, whhb, whhb + 65536,
                       h1cat, fin, hs, cs);
  }
  // Layer 1: same pattern, proj reads h1cat (complete after layer-0 phase)
  for (int k = 0; k <= NCHUNK; k++) {
    int do_proj = (k < NCHUNK);
    int do_lstm = (k > 0);
    hipLaunchKernelGGL((fused_chunk<256, 1>), dim3(do_proj ? 1056 : 32), dim3(512), 0, stream,
                       do_lstm, k - 1, k,
                       (const float*)nullptr, h1cat, (const int*)nullptr,
                       wih1b, wih1b + 131072,
                       b_ih_l1, b_hh_l1, b_ih_l1r, b_hh_l1r,
                       xpc0, xpc1, whhb + 131072, whhb + 196608,
                       h1cat, fin, hs, cs);
  }
  hipLaunchKernelGGL(fc_kernel, dim3(1), dim3(256), 0, stream, fin, fc_w, fc_b, out);
}

// Round 5
// 1866.545 us; speedup vs baseline: 1.4990x; 1.0004x over previous
//
#include <hip/hip_runtime.h>
#include <hip/hip_bf16.h>
#include <stdint.h>

// ---------------------------------------------------------------------------
// BiLSTM classifier: V=50000 E=100 H=128 B=128 T=1024 C=2. f32 I/O.
// Round 17 = r16 + __launch_bounds__(512, 2). Diagnosis: VGPR_Count=64 but
// the lstm path needs ~130 resident (wf[4][4] alone = 64) -> the compiler
// has been RELOADING Whh fragments every step (16 VMEM ops + vmcnt wait on
// the recurrence chain, ~200-300cyc L2 latency) because the default
// launch-bounds occupancy target capped registers for the proj-majority
// kernel. (512,2) = 2 waves/EU -> cap 256 VGPR -> wf stays resident.
// Everything else identical to r16 (proven 1867us): 32 lstm blocks, 8 rows,
// in-wave remap, packed-f32x2 gates, depth-2 xp prefetch, par-merged xpc.
// ---------------------------------------------------------------------------

typedef unsigned short u16;
typedef short bf16x8 __attribute__((ext_vector_type(8)));
typedef unsigned short ushort8v __attribute__((ext_vector_type(8)));
typedef float f32x4 __attribute__((ext_vector_type(4)));
typedef float f32x2 __attribute__((ext_vector_type(2)));

#define NB 128
#define NT 1024
#define NH 128
#define TC 128         // chunk length (steps)
#define NCHUNK (NT / TC)

#define L2E  1.44269504088896f
#define L2E2 2.88539008177793f

__device__ __forceinline__ u16 f2bf(float f) {
  union { float f; unsigned int i; } v; v.f = f;
  unsigned int i = v.i;
  return (u16)((i + 0x7FFFu + ((i >> 16) & 1u)) >> 16);  // RNE
}

#if __has_builtin(__builtin_amdgcn_exp2f)
__device__ __forceinline__ float fast_exp2(float x) { return __builtin_amdgcn_exp2f(x); }
#else
__device__ __forceinline__ float fast_exp2(float x) { return exp2f(x); }
#endif
#if __has_builtin(__builtin_amdgcn_rcpf)
__device__ __forceinline__ float fast_rcp(float x) { return __builtin_amdgcn_rcpf(x); }
#else
__device__ __forceinline__ float fast_rcp(float x) { return 1.0f / x; }
#endif

// LDS-only waits: lgkmcnt(0), vmcnt/expcnt unconstrained (imm 0xc07f, gfx9).
__device__ __forceinline__ void wait_lds() { __builtin_amdgcn_s_waitcnt(0xc07f); }
__device__ __forceinline__ void sync_lds() {
  __builtin_amdgcn_s_waitcnt(0xc07f);
  __builtin_amdgcn_s_barrier();
}

// ---------------------------------------------------------------------------
// pad w_ih_l0 f32 [512,100] -> bf16 [2][512][128], rows scaled by gate factor
__global__ void padw_kernel(const float* __restrict__ w0, const float* __restrict__ w1,
                            u16* __restrict__ out) {
  int idx = blockIdx.x * 256 + threadIdx.x;  // 131072
  int d = idx >> 16;
  int n = (idx >> 7) & 511;
  int k = idx & 127;
  float sc = ((n >> 7) == 2) ? L2E2 : L2E;
  const float* w = d ? w1 : w0;
  out[idx] = (k < 100) ? f2bf(w[n * 100 + k] * sc) : (u16)0;
}

// fused f32->bf16 convert for 6 weight arrays, rows scaled by gate factor.
__global__ void cvt6_kernel(const float* s0, const float* s1, const float* s2,
                            const float* s3, const float* s4, const float* s5,
                            u16* d0, u16* d1, u16* d2, u16* d3, u16* d4, u16* d5,
                            int n0, int n1, int n2, int n3, int n4, int n5) {
  int y = blockIdx.y;
  const float* s; u16* d; int n; int gs;
  switch (y) {
    case 0: s = s0; d = d0; n = n0; gs = 14; break;
    case 1: s = s1; d = d1; n = n1; gs = 14; break;
    case 2: s = s2; d = d2; n = n2; gs = 14; break;
    case 3: s = s3; d = d3; n = n3; gs = 14; break;
    case 4: s = s4; d = d4; n = n4; gs = 15; break;
    default: s = s5; d = d5; n = n5; gs = 15; break;
  }
  int i = blockIdx.x * 256 + threadIdx.x;
  if (i < n) {
    float sc = (((i >> gs) & 3) == 2) ? L2E2 : L2E;
    d[i] = f2bf(s[i] * sc);
  }
}

// ---------------------------------------------------------------------------
// Fused kernel. Blocks 0..31: lstm chunk `lc` (8 batch rows each, 2 dirs x
// 16 wg). Blocks 32..1055: proj chunk `pc`.
// xpc layout: [dir*16+wg][sl][rowpair4][gate4][col128][par2] u16
//             (8KB step tiles; one dword per lane per gate per step).
template <int PK, int LL>
__global__ __launch_bounds__(512, 2) void fused_chunk(
    int do_lstm, int lc, int pc,
    const float* __restrict__ Aemb, const u16* __restrict__ Ah,
    const int* __restrict__ X,
    const u16* __restrict__ W0, const u16* __restrict__ W1,   // [512][PK] bf16
    const float* __restrict__ bih0, const float* __restrict__ bhh0,
    const float* __restrict__ bih1, const float* __restrict__ bhh1,
    u16* __restrict__ xpc0, u16* __restrict__ xpc1,           // double buffer
    const u16* __restrict__ WHH0, const u16* __restrict__ WHH1,
    u16* __restrict__ OUT, float* __restrict__ FINALS,
    u16* __restrict__ HS, float* __restrict__ CS)
{
  // smem: proj As(18432)+Bs(18432)+toks(512)=37376; lstm hb(8704)+remap(16K)
  __shared__ __align__(16) unsigned char smem[37888];

  const int tid = threadIdx.x;
  const int lane = tid & 63, wv = tid >> 6;
  const int l15 = lane & 15, q = lane >> 4;

  if (blockIdx.x >= 32) {
    // ------------------------- proj part (8 waves, 64x32 wave tiles) -------
    constexpr int BK = 64;
    constexpr int LDA = 72;
    constexpr bool GATHER = (PK == 128);
    u16* As = (u16*)smem;
    u16* Bs = As + 128 * LDA;
    int* toks = (int*)(Bs + 128 * LDA);

    const int pb = blockIdx.x - 32;
    const int b = pb & 127;
    const int gate = (pb >> 7) & 3;
    const int nt0 = gate * 128;
    const int dir = pb >> 9;
    const u16* W = dir ? W1 : W0;
    u16* XPC = (pc & 1) ? xpc1 : xpc0;

    const int wr = wv >> 2, wc = wv & 3;   // 2 x 4 waves

    if (GATHER) {
      if (tid < 128) {
        int t = dir ? (NT - 1 - pc * TC - tid) : (pc * TC + tid);
        toks[tid] = X[b * NT + t];
      }
    }

    f32x4 acc[4][2];
#pragma unroll
    for (int a = 0; a < 4; a++)
#pragma unroll
      for (int bb = 0; bb < 2; bb++)
        acc[a][bb] = (f32x4){0.f, 0.f, 0.f, 0.f};

    const int srow = tid >> 3;        // 0..63
    const int sseg = (tid & 7) * 8;   // 0..56

    for (int k0 = 0; k0 < PK; k0 += BK) {
      __syncthreads();   // also covers toks on first iteration
#pragma unroll
      for (int p = 0; p < 2; p++) {
        int row = srow + p * 64;
        if (GATHER) {
          int tok = toks[row];
          const float* er = Aemb + (size_t)tok * 100;
          int kb = k0 + sseg;
          union { ushort8v v; u16 e[8]; } tu;
          if (kb + 8 <= 100) {
            f32x4 a0 = *(const f32x4*)&er[kb];
            f32x4 a1 = *(const f32x4*)&er[kb + 4];
#pragma unroll
            for (int j = 0; j < 4; j++) { tu.e[j] = f2bf(a0[j]); tu.e[4 + j] = f2bf(a1[j]); }
          } else {
#pragma unroll
            for (int j = 0; j < 8; j++) tu.e[j] = (kb + j < 100) ? f2bf(er[kb + j]) : (u16)0;
          }
          *(ushort8v*)&As[row * LDA + sseg] = tu.v;
        } else {
          int t = dir ? (NT - 1 - pc * TC - row) : (pc * TC + row);
          const u16* srcA = Ah + (size_t)(b * NT + t) * PK + k0 + sseg;
          *(ushort8v*)&As[row * LDA + sseg] = *(const ushort8v*)srcA;
        }
        const u16* srcB = W + (size_t)(nt0 + row) * PK + k0 + sseg;
        *(ushort8v*)&Bs[row * LDA + sseg] = *(const ushort8v*)srcB;
      }
      __syncthreads();
#pragma unroll
      for (int kk = 0; kk < BK; kk += 32) {
        bf16x8 af[4], bfr[2];
#pragma unroll
        for (int mt = 0; mt < 4; mt++)
          af[mt] = *(const bf16x8*)&As[(wr * 64 + mt * 16 + l15) * LDA + kk + q * 8];
#pragma unroll
        for (int nt = 0; nt < 2; nt++)
          bfr[nt] = *(const bf16x8*)&Bs[(wc * 32 + nt * 16 + l15) * LDA + kk + q * 8];
#pragma unroll
        for (int mt = 0; mt < 4; mt++)
#pragma unroll
          for (int nt = 0; nt < 2; nt++)
            acc[mt][nt] = __builtin_amdgcn_mfma_f32_16x16x32_bf16(af[mt], bfr[nt], acc[mt][nt], 0, 0, 0);
      }
    }

    const float* bih = dir ? bih1 : bih0;
    const float* bhh = dir ? bhh1 : bhh0;
    const float gsc = (gate == 2) ? L2E2 : L2E;
    // xpc: [dir*16 + b>>3][sl][rowpair = (b&7)>>1][gate][col][par = b&1]
    const int rb = b & 7;
    u16* xo = XPC + (size_t)(dir * 16 + (b >> 3)) * TC * 4096
                  + (size_t)(rb >> 1) * 1024 + gate * 256 + (rb & 1);
#pragma unroll
    for (int nt = 0; nt < 2; nt++) {
      int col = wc * 32 + nt * 16 + l15;          // within-gate col 0..127
      int n = nt0 + col;
      float bias = (bih[n] + bhh[n]) * gsc;
#pragma unroll
      for (int mt = 0; mt < 4; mt++) {
        int slb = wr * 64 + mt * 16 + q * 4;   // step-local index base
#pragma unroll
        for (int r = 0; r < 4; r++)
          xo[(size_t)(slb + r) * 4096 + col * 2] = f2bf(acc[mt][nt][r] + bias);
      }
    }
    return;
  }

  // --------------------------- lstm part (8 rows/WG + in-wave remap) -------
  if (!do_lstm) return;

  __builtin_amdgcn_s_setprio(3);

  const int wg = blockIdx.x & 15, dir = blockIdx.x >> 4;
  const int hc = 16 * wv + l15;
  const u16* XPC = (lc & 1) ? xpc1 : xpc0;

  const u16* Wp = dir ? WHH1 : WHH0;
  bf16x8 wf[4][4];
#pragma unroll
  for (int gi = 0; gi < 4; gi++)
#pragma unroll
    for (int kt = 0; kt < 4; kt++)
      wf[gi][kt] = *(const bf16x8*)&Wp[(gi * 128 + hc) * 128 + kt * 32 + q * 8];

  u16* hb = (u16*)smem;                               // [2][16*136] u16
  float* wsc = (float*)(smem + 8704 + wv * 2048);     // per-wave remap scratch

  f32x2 cst2;
  if (lc == 0) {
    for (int i = tid; i < 2 * 16 * 136; i += 512) hb[i] = 0;
    cst2 = (f32x2){0.f, 0.f};
  } else {
    // zero rows 8..15 of both planes (MFMA garbage guard)
    for (int i = tid; i < 2 * 8 * 136; i += 512) {
      int pl = i / (8 * 136), j = i - pl * (8 * 136);
      hb[pl * 2176 + 8 * 136 + j] = 0;
    }
    // load rows 0..7 (this lane owns rows 2q, 2q+1 at col hc)
#pragma unroll
    for (int rr = 0; rr < 2; rr++) {
      int row = 2 * q + rr;
      int g = (dir * 128 + wg * 8 + row) * 128 + hc;
      hb[row * 136 + hc] = HS[g];
      cst2[rr] = CS[g];
    }
  }

  // xp lane base: rowpair q, col hc -> one dword per gate per step.
  // u16 offset within step tile: q*1024 + gi*256 + hc*2; step stride 4096.
  const u16* xb = XPC + (size_t)(dir * 16 + wg) * TC * 4096 + q * 1024 + hc * 2;

#define LDXP(dst, s) do {                                        \
    const u16* nb_ = xb + (size_t)(s) * 4096;                    \
    _Pragma("unroll")                                            \
    for (int gi_ = 0; gi_ < 4; gi_++)                            \
      (dst)[gi_] = *(const unsigned int*)(nb_ + gi_ * 256);      \
  } while (0)

  // depth-2 prefetch: 4 rotating dword[4] buffers, static indexing
  unsigned int xp[4][4];
  LDXP(xp[0], 0);
  LDXP(xp[1], 1);

  const int t0 = dir ? (NT - 1 - lc * TC) : (lc * TC);
  const int tstep = dir ? -256 : 256;
  u16* optr[2];
  if (LL == 0) {
#pragma unroll
    for (int rr = 0; rr < 2; rr++)
      optr[rr] = OUT + ((size_t)(wg * 8 + 2 * q + rr) * NT + t0) * 256 + dir * 128 + hc;
  }

  const f32x4 zero4 = {0.f, 0.f, 0.f, 0.f};

  __syncthreads();

  int p = 0;
#pragma unroll 1
  for (int sl = 0; sl < TC; sl += 4) {
#pragma unroll
    for (int jj = 0; jj < 4; jj++) {
      const int scur = sl + jj;
      const unsigned int* xcur = xp[jj];
      unsigned int* xnxt = xp[(jj + 2) & 3];

      bf16x8 ah[4];
#pragma unroll
      for (int kt = 0; kt < 4; kt++)
        ah[kt] = *(const bf16x8*)&hb[p * 2176 + l15 * 136 + kt * 32 + q * 8];

      // prefetch step scur+2 (clamped: harmless re-read near chunk end)
      {
        int sn = scur + 2; if (sn > TC - 1) sn = TC - 1;
        LDXP(xnxt, sn);
      }

      // MFMA with zero C-init (xp added after remap)
      f32x4 acc[4];
#pragma unroll
      for (int gi = 0; gi < 4; gi++) {
        acc[gi] = __builtin_amdgcn_mfma_f32_16x16x32_bf16(ah[0], wf[gi][0], zero4, 0, 0, 0);
#pragma unroll
        for (int kt = 1; kt < 4; kt++)
          acc[gi] = __builtin_amdgcn_mfma_f32_16x16x32_bf16(ah[kt], wf[gi][kt], acc[gi], 0, 0, 0);
      }

      // in-wave remap: valid rows live in lanes q<2 (C rows q*4+r < 8);
      // scratch layout [gi][col l15][row 0..7] f32 -> each lane picks up
      // rows {2q, 2q+1} at its col. Wave-internal: lgkm wait, no barrier.
      if (lane < 32) {
#pragma unroll
        for (int gi = 0; gi < 4; gi++)
          *(f32x4*)&wsc[gi * 128 + l15 * 8 + (lane >> 4) * 4] = acc[gi];
      }
      wait_lds();
      f32x2 ar[4];
#pragma unroll
      for (int gi = 0; gi < 4; gi++)
        ar[gi] = *(const f32x2*)&wsc[gi * 128 + l15 * 8 + q * 2];

      // unpack xp dwords -> f32x2 over rr (par0 -> <<16, par1 -> mask)
      f32x2 xv[4];
#pragma unroll
      for (int gi = 0; gi < 4; gi++) {
        union { unsigned int u; float f; } lo, hi;
        lo.u = xcur[gi] << 16;
        hi.u = xcur[gi] & 0xFFFF0000u;
        xv[gi][0] = lo.f; xv[gi][1] = hi.f;
      }

      // packed gate math (rr = vector lane). Preacts pre-scaled by L2E/L2E2.
      f32x2 pi = ar[0] + xv[0];
      f32x2 pf = ar[1] + xv[1];
      f32x2 pg = ar[2] + xv[2];
      f32x2 po = ar[3] + xv[3];
      f32x2 ei, ef, eg, eo;
      ei[0] = fast_exp2(pi[0]); ei[1] = fast_exp2(pi[1]);
      ef[0] = fast_exp2(pf[0]); ef[1] = fast_exp2(pf[1]);
      eg[0] = fast_exp2(pg[0]); eg[1] = fast_exp2(pg[1]);
      eo[0] = fast_exp2(po[0]); eo[1] = fast_exp2(po[1]);
      f32x2 A  = 1.f + ef;
      f32x2 Bv = 1.f + ei;
      f32x2 Cg = 1.f + eg;
      f32x2 BC = Bv * Cg;
      f32x2 num = cst2 * ef * BC + ei * (eg - 1.f) * A;
      f32x2 den = A * BC;
      f32x2 rden; rden[0] = fast_rcp(den[0]); rden[1] = fast_rcp(den[1]);
      f32x2 cn = num * rden;
      cst2 = cn;
      f32x2 tc2 = L2E2 * cn;
      f32x2 ec; ec[0] = fast_exp2(tc2[0]); ec[1] = fast_exp2(tc2[1]);
      f32x2 d2 = (1.f + eo) * (1.f + ec);
      f32x2 r2; r2[0] = fast_rcp(d2[0]); r2[1] = fast_rcp(d2[1]);
      f32x2 hv2 = eo * (ec - 1.f) * r2;

#pragma unroll
      for (int rr = 0; rr < 2; rr++) {
        u16 hbv = f2bf(hv2[rr]);
        int row = 2 * q + rr;
        hb[(p ^ 1) * 2176 + row * 136 + hc] = hbv;
        if (LL == 0) {
          *optr[rr] = hbv;
          optr[rr] += tstep;
        }
        if (scur == TC - 1) {
          int g = (dir * 128 + wg * 8 + row) * 128 + hc;
          HS[g] = hbv;
          CS[g] = cst2[rr];
          if (LL == 1 && lc == NCHUNK - 1)
            FINALS[(wg * 8 + row) * 256 + dir * 128 + hc] = hv2[rr];
        }
      }
      sync_lds();   // h-exchange: lgkmcnt(0)+barrier; VMEM stays in flight
      p ^= 1;
    }
  }
#undef LDXP
}

// ---------------------------------------------------------------------------
// fc: out[b][c] = finals[b][:] . fc_w[c][:] + fc_b[c]  (all f32)
__global__ void fc_kernel(const float* __restrict__ finals, const float* __restrict__ fcw,
                          const float* __restrict__ fcb, float* __restrict__ out) {
  int tid = threadIdx.x;  // 256 = 128 b x 2 c
  int b = tid >> 1, cc = tid & 1;
  float s = fcb[cc];
  for (int k = 0; k < 256; k++) s += finals[b * 256 + k] * fcw[cc * 256 + k];
  out[b * 2 + cc] = s;
}

// ---------------------------------------------------------------------------
extern "C" void kernel_launch(void* const* d_in, const int* in_sizes, int n_in,
                              void* d_out, int out_size, void* d_ws, size_t ws_size,
                              hipStream_t stream) {
  const int*   x        = (const int*)d_in[0];
  const float* emb      = (const float*)d_in[1];
  const float* w_ih_l0  = (const float*)d_in[2];
  const float* w_hh_l0  = (const float*)d_in[3];
  const float* b_ih_l0  = (const float*)d_in[4];
  const float* b_hh_l0  = (const float*)d_in[5];
  const float* w_ih_l0r = (const float*)d_in[6];
  const float* w_hh_l0r = (const float*)d_in[7];
  const float* b_ih_l0r = (const float*)d_in[8];
  const float* b_hh_l0r = (const float*)d_in[9];
  const float* w_ih_l1  = (const float*)d_in[10];
  const float* w_hh_l1  = (const float*)d_in[11];
  const float* b_ih_l1  = (const float*)d_in[12];
  const float* b_hh_l1  = (const float*)d_in[13];
  const float* w_ih_l1r = (const float*)d_in[14];
  const float* w_hh_l1r = (const float*)d_in[15];
  const float* b_ih_l1r = (const float*)d_in[16];
  const float* b_hh_l1r = (const float*)d_in[17];
  const float* fc_w     = (const float*)d_in[18];
  const float* fc_b     = (const float*)d_in[19];
  float* out = (float*)d_out;

  // workspace layout — total 135,856,128 B (r8-r16 footprint, proven)
  char* ws = (char*)d_ws;
  size_t off = 0;
  u16*   h1cat = (u16*)(ws + off);   off += 67108864;  // [NB*NT][256] bf16
  u16*   xpc0  = (u16*)(ws + off);   off += 33554432;  // xp double buffer 0
  u16*   xpc1  = (u16*)(ws + off);   off += 33554432;  // xp double buffer 1
  u16*   w0pad = (u16*)(ws + off);   off += 262144;    // [2][512][128] bf16 (scaled)
  u16*   wih1b = (u16*)(ws + off);   off += 524288;    // [2][512][256] bf16 (scaled)
  u16*   whhb  = (u16*)(ws + off);   off += 524288;    // [4][512][128] bf16 (scaled)
  u16*   hs    = (u16*)(ws + off);   off += 65536;     // [2][128][128] bf16
  float* cs    = (float*)(ws + off); off += 131072;    // [2][128][128] f32
  float* fin   = (float*)(ws + off); off += 131072;    // [128][256] f32
  if (ws_size < off) return;  // constant across calls -> same work every call

  hipLaunchKernelGGL(padw_kernel, dim3(512), dim3(256), 0, stream,
                     w_ih_l0, w_ih_l0r, w0pad);
  hipLaunchKernelGGL(cvt6_kernel, dim3(512, 6), dim3(256), 0, stream,
                     w_hh_l0, w_hh_l0r, w_hh_l1, w_hh_l1r, w_ih_l1, w_ih_l1r,
                     whhb, whhb + 65536, whhb + 131072, whhb + 196608,
                     wih1b, wih1b + 131072,
                     65536, 65536, 65536, 65536, 131072, 131072);

  // Layer 0: launch k does proj0(k) [k<8] fused with lstm0(k-1) [k>0]
  for (int k = 0; k <= NCHUNK; k++) {
    int do_proj = (k < NCHUNK);
    int do_lstm = (k > 0);
    hipLaunchKernelGGL((fused_chunk<128, 0>), dim3(do_proj ? 1056 : 32), dim3(512), 0, stream,
                       do_lstm, k - 1, k,
                       emb, (const u16*)nullptr, x, w0pad, w0pad + 65536,
                       b_ih_l0, b_hh_l0, b_ih_l0r, b_hh_l0r,
                       xpc0, xpc1, whhb, whhb + 65536,
                       h1cat, fin, hs, cs);
  }
  // Layer 1: same pattern, proj reads h1cat (complete after layer-0 phase)
  for (int k = 0; k <= NCHUNK; k++) {
    int do_proj = (k < NCHUNK);
    int do_lstm = (k > 0);
    hipLaunchKernelGGL((fused_chunk<256, 1>), dim3(do_proj ? 1056 : 32), dim3(512), 0, stream,
                       do_lstm, k - 1, k,
                       (const float*)nullptr, h1cat, (const int*)nullptr,
                       wih1b, wih1b + 131072,
                       b_ih_l1, b_hh_l1, b_ih_l1r, b_hh_l1r,
                       xpc0, xpc1, whhb + 131072, whhb + 196608,
                       h1cat, fin, hs, cs);
  }
  hipLaunchKernelGGL(fc_kernel, dim3(1), dim3(256), 0, stream, fin, fc_w, fc_b, out);
}

// Round 7
// 1559.112 us; speedup vs baseline: 1.7945x; 1.1972x over previous
//
#include <hip/hip_runtime.h>
#include <hip/hip_bf16.h>
#include <stdint.h>

// ---------------------------------------------------------------------------
// BiLSTM classifier: V=50000 E=100 H=128 B=128 T=1024 C=2. f32 I/O.
// Round 19 = r18 with the acc redistribution done via __shfl_xor(32) +
// zero-merge instead of v_permlane32_swap_b32 (r18 failed: the permlane swap
// DIRECTION was guessed wrong; shfl_xor/ds_bpermute semantics are exact).
// Zero-merge trick: hb rows 8..15 are zero, so each lane's unwanted acc half
// is exactly 0 -> ar = own_reg + shfl_xor(partner_reg, 32), no cndmask.
// This keeps r18's goal: the per-step remap moves from the LDS-bank path
// (32 ds_write_b128 + 32 ds_read_b64 + 832 conflict-cyc/step) to 8 bank-free
// ds_bpermute + 8 VALU adds. xpc [sl][colgrp8][gate4][lane64][rr2] layout
// (coalesced dword loads), row0 ownership, depth-2 prefetch all retained.
// ---------------------------------------------------------------------------

typedef unsigned short u16;
typedef short bf16x8 __attribute__((ext_vector_type(8)));
typedef unsigned short ushort8v __attribute__((ext_vector_type(8)));
typedef float f32x4 __attribute__((ext_vector_type(4)));
typedef float f32x2 __attribute__((ext_vector_type(2)));

#define NB 128
#define NT 1024
#define NH 128
#define TC 128         // chunk length (steps)
#define NCHUNK (NT / TC)

#define L2E  1.44269504088896f
#define L2E2 2.88539008177793f

__device__ __forceinline__ u16 f2bf(float f) {
  union { float f; unsigned int i; } v; v.f = f;
  unsigned int i = v.i;
  return (u16)((i + 0x7FFFu + ((i >> 16) & 1u)) >> 16);  // RNE
}

#if __has_builtin(__builtin_amdgcn_exp2f)
__device__ __forceinline__ float fast_exp2(float x) { return __builtin_amdgcn_exp2f(x); }
#else
__device__ __forceinline__ float fast_exp2(float x) { return exp2f(x); }
#endif
#if __has_builtin(__builtin_amdgcn_rcpf)
__device__ __forceinline__ float fast_rcp(float x) { return __builtin_amdgcn_rcpf(x); }
#else
__device__ __forceinline__ float fast_rcp(float x) { return 1.0f / x; }
#endif

// LDS-only waits: lgkmcnt(0), vmcnt/expcnt unconstrained (imm 0xc07f, gfx9).
__device__ __forceinline__ void sync_lds() {
  __builtin_amdgcn_s_waitcnt(0xc07f);
  __builtin_amdgcn_s_barrier();
}

// ---------------------------------------------------------------------------
// pad w_ih_l0 f32 [512,100] -> bf16 [2][512][128], rows scaled by gate factor
__global__ void padw_kernel(const float* __restrict__ w0, const float* __restrict__ w1,
                            u16* __restrict__ out) {
  int idx = blockIdx.x * 256 + threadIdx.x;  // 131072
  int d = idx >> 16;
  int n = (idx >> 7) & 511;
  int k = idx & 127;
  float sc = ((n >> 7) == 2) ? L2E2 : L2E;
  const float* w = d ? w1 : w0;
  out[idx] = (k < 100) ? f2bf(w[n * 100 + k] * sc) : (u16)0;
}

// fused f32->bf16 convert for 6 weight arrays, rows scaled by gate factor.
__global__ void cvt6_kernel(const float* s0, const float* s1, const float* s2,
                            const float* s3, const float* s4, const float* s5,
                            u16* d0, u16* d1, u16* d2, u16* d3, u16* d4, u16* d5,
                            int n0, int n1, int n2, int n3, int n4, int n5) {
  int y = blockIdx.y;
  const float* s; u16* d; int n; int gs;
  switch (y) {
    case 0: s = s0; d = d0; n = n0; gs = 14; break;
    case 1: s = s1; d = d1; n = n1; gs = 14; break;
    case 2: s = s2; d = d2; n = n2; gs = 14; break;
    case 3: s = s3; d = d3; n = n3; gs = 14; break;
    case 4: s = s4; d = d4; n = n4; gs = 15; break;
    default: s = s5; d = d5; n = n5; gs = 15; break;
  }
  int i = blockIdx.x * 256 + threadIdx.x;
  if (i < n) {
    float sc = (((i >> gs) & 3) == 2) ? L2E2 : L2E;
    d[i] = f2bf(s[i] * sc);
  }
}

// ---------------------------------------------------------------------------
// Fused kernel. Blocks 0..31: lstm chunk `lc` (8 batch rows each, 2 dirs x
// 16 wg). Blocks 32..1055: proj chunk `pc`.
// xpc layout: [dir*16+wg][sl][colgrp8][gate4][lane64-as-u32][rr2] u16
//             (8KB step tiles; one dword per lane per gate per step).
template <int PK, int LL>
__global__ __launch_bounds__(512, 2) void fused_chunk(
    int do_lstm, int lc, int pc,
    const float* __restrict__ Aemb, const u16* __restrict__ Ah,
    const int* __restrict__ X,
    const u16* __restrict__ W0, const u16* __restrict__ W1,   // [512][PK] bf16
    const float* __restrict__ bih0, const float* __restrict__ bhh0,
    const float* __restrict__ bih1, const float* __restrict__ bhh1,
    u16* __restrict__ xpc0, u16* __restrict__ xpc1,           // double buffer
    const u16* __restrict__ WHH0, const u16* __restrict__ WHH1,
    u16* __restrict__ OUT, float* __restrict__ FINALS,
    u16* __restrict__ HS, float* __restrict__ CS)
{
  // smem: proj As(18432)+Bs(18432)+toks(512)=37376; lstm hb(8704)
  __shared__ __align__(16) unsigned char smem[37888];

  const int tid = threadIdx.x;
  const int lane = tid & 63, wv = tid >> 6;
  const int l15 = lane & 15, q = lane >> 4;

  if (blockIdx.x >= 32) {
    // ------------------------- proj part (8 waves, 64x32 wave tiles) -------
    constexpr int BK = 64;
    constexpr int LDA = 72;
    constexpr bool GATHER = (PK == 128);
    u16* As = (u16*)smem;
    u16* Bs = As + 128 * LDA;
    int* toks = (int*)(Bs + 128 * LDA);

    const int pb = blockIdx.x - 32;
    const int b = pb & 127;
    const int gate = (pb >> 7) & 3;
    const int nt0 = gate * 128;
    const int dir = pb >> 9;
    const u16* W = dir ? W1 : W0;
    u16* XPC = (pc & 1) ? xpc1 : xpc0;

    const int wr = wv >> 2, wc = wv & 3;   // 2 x 4 waves

    if (GATHER) {
      if (tid < 128) {
        int t = dir ? (NT - 1 - pc * TC - tid) : (pc * TC + tid);
        toks[tid] = X[b * NT + t];
      }
    }

    f32x4 acc[4][2];
#pragma unroll
    for (int a = 0; a < 4; a++)
#pragma unroll
      for (int bb = 0; bb < 2; bb++)
        acc[a][bb] = (f32x4){0.f, 0.f, 0.f, 0.f};

    const int srow = tid >> 3;        // 0..63
    const int sseg = (tid & 7) * 8;   // 0..56

    for (int k0 = 0; k0 < PK; k0 += BK) {
      __syncthreads();   // also covers toks on first iteration
#pragma unroll
      for (int p = 0; p < 2; p++) {
        int row = srow + p * 64;
        if (GATHER) {
          int tok = toks[row];
          const float* er = Aemb + (size_t)tok * 100;
          int kb = k0 + sseg;
          union { ushort8v v; u16 e[8]; } tu;
          if (kb + 8 <= 100) {
            f32x4 a0 = *(const f32x4*)&er[kb];
            f32x4 a1 = *(const f32x4*)&er[kb + 4];
#pragma unroll
            for (int j = 0; j < 4; j++) { tu.e[j] = f2bf(a0[j]); tu.e[4 + j] = f2bf(a1[j]); }
          } else {
#pragma unroll
            for (int j = 0; j < 8; j++) tu.e[j] = (kb + j < 100) ? f2bf(er[kb + j]) : (u16)0;
          }
          *(ushort8v*)&As[row * LDA + sseg] = tu.v;
        } else {
          int t = dir ? (NT - 1 - pc * TC - row) : (pc * TC + row);
          const u16* srcA = Ah + (size_t)(b * NT + t) * PK + k0 + sseg;
          *(ushort8v*)&As[row * LDA + sseg] = *(const ushort8v*)srcA;
        }
        const u16* srcB = W + (size_t)(nt0 + row) * PK + k0 + sseg;
        *(ushort8v*)&Bs[row * LDA + sseg] = *(const ushort8v*)srcB;
      }
      __syncthreads();
#pragma unroll
      for (int kk = 0; kk < BK; kk += 32) {
        bf16x8 af[4], bfr[2];
#pragma unroll
        for (int mt = 0; mt < 4; mt++)
          af[mt] = *(const bf16x8*)&As[(wr * 64 + mt * 16 + l15) * LDA + kk + q * 8];
#pragma unroll
        for (int nt = 0; nt < 2; nt++)
          bfr[nt] = *(const bf16x8*)&Bs[(wc * 32 + nt * 16 + l15) * LDA + kk + q * 8];
#pragma unroll
        for (int mt = 0; mt < 4; mt++)
#pragma unroll
          for (int nt = 0; nt < 2; nt++)
            acc[mt][nt] = __builtin_amdgcn_mfma_f32_16x16x32_bf16(af[mt], bfr[nt], acc[mt][nt], 0, 0, 0);
      }
    }

    const float* bih = dir ? bih1 : bih0;
    const float* bhh = dir ? bhh1 : bhh0;
    const float gsc = (gate == 2) ? L2E2 : L2E;
    // xpc dest for value (sl, row=b&7, gate, col):
    //   u16 off = sl*4096 + (col>>4)*512 + gate*128 + q(row)*32 + (col&15)*2
    //           + (row&1), with q(row): rowpair=row>>1, q=((rp&1)<<1)|(rp>>1)
    const int rb = b & 7;
    u16* xo = XPC + (size_t)(dir * 16 + (b >> 3)) * TC * 4096
                  + ((rb >> 1) & 1) * 64 + ((rb >> 2) & 1) * 32 + (rb & 1) + l15 * 2;
#pragma unroll
    for (int nt = 0; nt < 2; nt++) {
      int col = wc * 32 + nt * 16 + l15;          // within-gate col 0..127
      int n = nt0 + col;
      float bias = (bih[n] + bhh[n]) * gsc;
      int bnt = ((wc * 2 + nt) * 4 + gate) * 128;
#pragma unroll
      for (int mt = 0; mt < 4; mt++) {
        int slb = wr * 64 + mt * 16 + q * 4;   // step-local index base
#pragma unroll
        for (int r = 0; r < 4; r++)
          xo[(size_t)(slb + r) * 4096 + bnt] = f2bf(acc[mt][nt][r] + bias);
      }
    }
    return;
  }

  // ----------------- lstm part (8 rows/WG + shfl_xor zero-merge remap) -----
  if (!do_lstm) return;

  __builtin_amdgcn_s_setprio(3);

  const int wg = blockIdx.x & 15, dir = blockIdx.x >> 4;
  const int hc = 16 * wv + l15;
  const u16* XPC = (lc & 1) ? xpc1 : xpc0;

  // lane row ownership: rows {row0, row0+1}, col hc
  // q=0 -> {0,1}, q=1 -> {4,5}, q=2 -> {2,3}, q=3 -> {6,7}
  const int row0 = ((lane >> 4) & 1) * 4 + (lane >> 5) * 2;

  const u16* Wp = dir ? WHH1 : WHH0;
  bf16x8 wf[4][4];
#pragma unroll
  for (int gi = 0; gi < 4; gi++)
#pragma unroll
    for (int kt = 0; kt < 4; kt++)
      wf[gi][kt] = *(const bf16x8*)&Wp[(gi * 128 + hc) * 128 + kt * 32 + q * 8];

  u16* hb = (u16*)smem;   // [2][16*136] u16

  const int g0 = (dir * 128 + wg * 8 + row0) * 128 + hc;  // HS/CS row0 slot
  f32x2 cst2;
  if (lc == 0) {
    for (int i = tid; i < 2 * 16 * 136; i += 512) hb[i] = 0;
    cst2 = (f32x2){0.f, 0.f};
  } else {
    // zero rows 8..15 of both planes (MFMA garbage guard + zero-merge basis)
    for (int i = tid; i < 2 * 8 * 136; i += 512) {
      int pl = i / (8 * 136), j = i - pl * (8 * 136);
      hb[pl * 2176 + 8 * 136 + j] = 0;
    }
    // restore rows 0..7 plane 0: each lane covers its 2 rows at col hc
    hb[row0 * 136 + hc] = HS[g0];
    hb[(row0 + 1) * 136 + hc] = HS[g0 + 128];
    cst2[0] = CS[g0];
    cst2[1] = CS[g0 + 128];
  }

  // xp lane base: one dword per gate per step at (colgrp=wv, gate, lane)
  const u16* xb = XPC + (size_t)(dir * 16 + wg) * TC * 4096 + wv * 512 + lane * 2;

#define LDXP(dst, s) do {                                        \
    const u16* nb_ = xb + (size_t)(s) * 4096;                    \
    _Pragma("unroll")                                            \
    for (int gi_ = 0; gi_ < 4; gi_++)                            \
      (dst)[gi_] = *(const unsigned int*)(nb_ + gi_ * 128);      \
  } while (0)

  // depth-2 prefetch: 4 rotating dword[4] buffers, static indexing
  unsigned int xp[4][4];
  LDXP(xp[0], 0);
  LDXP(xp[1], 1);

  const int t0 = dir ? (NT - 1 - lc * TC) : (lc * TC);
  const int tstep = dir ? -256 : 256;
  u16* optr[2];
  if (LL == 0) {
#pragma unroll
    for (int rr = 0; rr < 2; rr++)
      optr[rr] = OUT + ((size_t)(wg * 8 + row0 + rr) * NT + t0) * 256 + dir * 128 + hc;
  }

  const f32x4 zero4 = {0.f, 0.f, 0.f, 0.f};

  __syncthreads();

  int p = 0;
#pragma unroll 1
  for (int sl = 0; sl < TC; sl += 4) {
#pragma unroll
    for (int jj = 0; jj < 4; jj++) {
      const int scur = sl + jj;
      const unsigned int* xcur = xp[jj];
      unsigned int* xnxt = xp[(jj + 2) & 3];

      bf16x8 ah[4];
#pragma unroll
      for (int kt = 0; kt < 4; kt++)
        ah[kt] = *(const bf16x8*)&hb[p * 2176 + l15 * 136 + kt * 32 + q * 8];

      // prefetch step scur+2 (clamped: harmless re-read near chunk end)
      {
        int sn = scur + 2; if (sn > TC - 1) sn = TC - 1;
        LDXP(xnxt, sn);
      }

      // MFMA with zero C-init (xp added after remap)
      f32x4 acc[4];
#pragma unroll
      for (int gi = 0; gi < 4; gi++) {
        acc[gi] = __builtin_amdgcn_mfma_f32_16x16x32_bf16(ah[0], wf[gi][0], zero4, 0, 0, 0);
#pragma unroll
        for (int kt = 1; kt < 4; kt++)
          acc[gi] = __builtin_amdgcn_mfma_f32_16x16x32_bf16(ah[kt], wf[gi][kt], acc[gi], 0, 0, 0);
      }

      // shfl_xor(32) zero-merge remap (bank-free ds_bpermute, exact semantics):
      // lanes<32: own regs {0,1} valid (rows 0/1 or 4/5), partner regs {2,3}
      // are MFMA over zero rows -> 0. lanes>=32: own regs zero, partner regs
      // {2,3} valid (rows 2/3 or 6/7). Sum = correct value for all lanes.
      f32x2 ar[4];
#pragma unroll
      for (int gi = 0; gi < 4; gi++) {
        float s2 = __shfl_xor(acc[gi][2], 32);
        float s3 = __shfl_xor(acc[gi][3], 32);
        ar[gi][0] = acc[gi][0] + s2;
        ar[gi][1] = acc[gi][1] + s3;
      }

      // unpack xp dwords -> f32x2 over rr (rr0 -> <<16, rr1 -> mask)
      f32x2 xv[4];
#pragma unroll
      for (int gi = 0; gi < 4; gi++) {
        union { unsigned int u; float f; } lo, hi;
        lo.u = xcur[gi] << 16;
        hi.u = xcur[gi] & 0xFFFF0000u;
        xv[gi][0] = lo.f; xv[gi][1] = hi.f;
      }

      // packed gate math (rr = vector lane). Preacts pre-scaled by L2E/L2E2.
      f32x2 pi = ar[0] + xv[0];
      f32x2 pf = ar[1] + xv[1];
      f32x2 pg = ar[2] + xv[2];
      f32x2 po = ar[3] + xv[3];
      f32x2 ei, ef, eg, eo;
      ei[0] = fast_exp2(pi[0]); ei[1] = fast_exp2(pi[1]);
      ef[0] = fast_exp2(pf[0]); ef[1] = fast_exp2(pf[1]);
      eg[0] = fast_exp2(pg[0]); eg[1] = fast_exp2(pg[1]);
      eo[0] = fast_exp2(po[0]); eo[1] = fast_exp2(po[1]);
      f32x2 A  = 1.f + ef;
      f32x2 Bv = 1.f + ei;
      f32x2 Cg = 1.f + eg;
      f32x2 BC = Bv * Cg;
      f32x2 num = cst2 * ef * BC + ei * (eg - 1.f) * A;
      f32x2 den = A * BC;
      f32x2 rden; rden[0] = fast_rcp(den[0]); rden[1] = fast_rcp(den[1]);
      f32x2 cn = num * rden;
      cst2 = cn;
      f32x2 tc2 = L2E2 * cn;
      f32x2 ec; ec[0] = fast_exp2(tc2[0]); ec[1] = fast_exp2(tc2[1]);
      f32x2 d2 = (1.f + eo) * (1.f + ec);
      f32x2 r2; r2[0] = fast_rcp(d2[0]); r2[1] = fast_rcp(d2[1]);
      f32x2 hv2 = eo * (ec - 1.f) * r2;

      u16 hbv0 = f2bf(hv2[0]);
      u16 hbv1 = f2bf(hv2[1]);
      hb[(p ^ 1) * 2176 + row0 * 136 + hc] = hbv0;
      hb[(p ^ 1) * 2176 + (row0 + 1) * 136 + hc] = hbv1;
      if (LL == 0) {
        *optr[0] = hbv0; optr[0] += tstep;
        *optr[1] = hbv1; optr[1] += tstep;
      }
      if (scur == TC - 1) {
        HS[g0] = hbv0;
        HS[g0 + 128] = hbv1;
        CS[g0] = cst2[0];
        CS[g0 + 128] = cst2[1];
        if (LL == 1 && lc == NCHUNK - 1) {
          FINALS[(wg * 8 + row0) * 256 + dir * 128 + hc] = hv2[0];
          FINALS[(wg * 8 + row0 + 1) * 256 + dir * 128 + hc] = hv2[1];
        }
      }
      sync_lds();   // h-exchange: lgkmcnt(0)+barrier; VMEM stays in flight
      p ^= 1;
    }
  }
#undef LDXP
}

// ---------------------------------------------------------------------------
// fc: out[b][c] = finals[b][:] . fc_w[c][:] + fc_b[c]  (all f32)
__global__ void fc_kernel(const float* __restrict__ finals, const float* __restrict__ fcw,
                          const float* __restrict__ fcb, float* __restrict__ out) {
  int tid = threadIdx.x;  // 256 = 128 b x 2 c
  int b = tid >> 1, cc = tid & 1;
  float s = fcb[cc];
  for (int k = 0; k < 256; k++) s += finals[b * 256 + k] * fcw[cc * 256 + k];
  out[b * 2 + cc] = s;
}

// ---------------------------------------------------------------------------
extern "C" void kernel_launch(void* const* d_in, const int* in_sizes, int n_in,
                              void* d_out, int out_size, void* d_ws, size_t ws_size,
                              hipStream_t stream) {
  const int*   x        = (const int*)d_in[0];
  const float* emb      = (const float*)d_in[1];
  const float* w_ih_l0  = (const float*)d_in[2];
  const float* w_hh_l0  = (const float*)d_in[3];
  const float* b_ih_l0  = (const float*)d_in[4];
  const float* b_hh_l0  = (const float*)d_in[5];
  const float* w_ih_l0r = (const float*)d_in[6];
  const float* w_hh_l0r = (const float*)d_in[7];
  const float* b_ih_l0r = (const float*)d_in[8];
  const float* b_hh_l0r = (const float*)d_in[9];
  const float* w_ih_l1  = (const float*)d_in[10];
  const float* w_hh_l1  = (const float*)d_in[11];
  const float* b_ih_l1  = (const float*)d_in[12];
  const float* b_hh_l1  = (const float*)d_in[13];
  const float* w_ih_l1r = (const float*)d_in[14];
  const float* w_hh_l1r = (const float*)d_in[15];
  const float* b_ih_l1r = (const float*)d_in[16];
  const float* b_hh_l1r = (const float*)d_in[17];
  const float* fc_w     = (const float*)d_in[18];
  const float* fc_b     = (const float*)d_in[19];
  float* out = (float*)d_out;

  // workspace layout — total 135,856,128 B (r8-r17 footprint, proven)
  char* ws = (char*)d_ws;
  size_t off = 0;
  u16*   h1cat = (u16*)(ws + off);   off += 67108864;  // [NB*NT][256] bf16
  u16*   xpc0  = (u16*)(ws + off);   off += 33554432;  // xp double buffer 0
  u16*   xpc1  = (u16*)(ws + off);   off += 33554432;  // xp double buffer 1
  u16*   w0pad = (u16*)(ws + off);   off += 262144;    // [2][512][128] bf16 (scaled)
  u16*   wih1b = (u16*)(ws + off);   off += 524288;    // [2][512][256] bf16 (scaled)
  u16*   whhb  = (u16*)(ws + off);   off += 524288;    // [4][512][128] bf16 (scaled)
  u16*   hs    = (u16*)(ws + off);   off += 65536;     // [2][128][128] bf16
  float* cs    = (float*)(ws + off); off += 131072;    // [2][128][128] f32
  float* fin   = (float*)(ws + off); off += 131072;    // [128][256] f32
  if (ws_size < off) return;  // constant across calls -> same work every call

  hipLaunchKernelGGL(padw_kernel, dim3(512), dim3(256), 0, stream,
                     w_ih_l0, w_ih_l0r, w0pad);
  hipLaunchKernelGGL(cvt6_kernel, dim3(512, 6), dim3(256), 0, stream,
                     w_hh_l0, w_hh_l0r, w_hh_l1, w_hh_l1r, w_ih_l1, w_ih_l1r,
                     whhb, whhb + 65536, whhb + 131072, whhb + 196608,
                     wih1b, wih1b + 131072,
                     65536, 65536, 65536, 65536, 131072, 131072);

  // Layer 0: launch k does proj0(k) [k<8] fused with lstm0(k-1) [k>0]
  for (int k = 0; k <= NCHUNK; k++) {
    int do_proj = (k < NCHUNK);
    int do_lstm = (k > 0);
    hipLaunchKernelGGL((fused_chunk<128, 0>), dim3(do_proj ? 1056 : 32), dim3(512), 0, stream,
                       do_lstm, k - 1, k,
                       emb, (const u16*)nullptr, x, w0pad, w0pad + 65536,
                       b_ih_l0, b_hh_l0, b_ih_l0r, b_hh_l0r,
                       xpc0, xpc1, whhb, whhb + 65536,
                       h1cat, fin, hs, cs);
  }
  // Layer 1: same pattern, proj reads h1cat (complete after layer-0 phase)
  for (int k = 0; k <= NCHUNK; k++) {
    int do_proj = (k < NCHUNK);
    int do_lstm = (k > 0);
    hipLaunchKernelGGL((fused_chunk<256, 1>), dim3(do_proj ? 1056 : 32), dim3(512), 0, stream,
                       do_lstm, k - 1, k,
                       (const float*)nullptr, h1cat, (const int*)nullptr,
                       wih1b, wih1b + 131072,
                       b_ih_l1, b_hh_l1, b_ih_l1r, b_hh_l1r,
                       xpc0, xpc1, whhb + 131072, whhb + 196608,
                       h1cat, fin, hs, cs);
  }
  hipLaunchKernelGGL(fc_kernel, dim3(1), dim3(256), 0, stream, fin, fc_w, fc_b, out);
}

// Round 8
// 1469.231 us; speedup vs baseline: 1.9043x; 1.0612x over previous
//
#include <hip/hip_runtime.h>
#include <hip/hip_bf16.h>
#include <stdint.h>

// ---------------------------------------------------------------------------
// BiLSTM classifier: V=50000 E=100 H=128 B=128 T=1024 C=2. f32 I/O.
// Round 20 = r19 + row-duplication remap (zero DS-ops on the exchange).
// Evidence: r19 (-13%) confirmed the LDS-pipe/contention model: lstm shares
// its CU with ~3 proj blocks whose ds_read_b128 streams keep the (FIFO,
// priority-blind) LDS pipe busy; every lstm DS op waits 3-5x. r19 still had
// 8 ds_bpermute (shfl_xor) per step on the chain. r20: h is written TWICE
// into hb (rows 0-7 and dup rows 8-15, +2 off-chain ds_write_b16); the MFMA
// A-operand rows 8-15 become row copies, so lane(l15,q) regs r hold batch
// row (4q+r) mod 8 and the remap is a pure per-lane register select
// ar = (lane<32) ? acc[{0,1}] : acc[{2,3}]  (8 v_cndmask, no LDS).
// row0 = {0,4,2,6}[q] unchanged -> all external mappings unchanged.
// ---------------------------------------------------------------------------

typedef unsigned short u16;
typedef short bf16x8 __attribute__((ext_vector_type(8)));
typedef unsigned short ushort8v __attribute__((ext_vector_type(8)));
typedef float f32x4 __attribute__((ext_vector_type(4)));
typedef float f32x2 __attribute__((ext_vector_type(2)));

#define NB 128
#define NT 1024
#define NH 128
#define TC 128         // chunk length (steps)
#define NCHUNK (NT / TC)

#define L2E  1.44269504088896f
#define L2E2 2.88539008177793f

__device__ __forceinline__ u16 f2bf(float f) {
  union { float f; unsigned int i; } v; v.f = f;
  unsigned int i = v.i;
  return (u16)((i + 0x7FFFu + ((i >> 16) & 1u)) >> 16);  // RNE
}

#if __has_builtin(__builtin_amdgcn_exp2f)
__device__ __forceinline__ float fast_exp2(float x) { return __builtin_amdgcn_exp2f(x); }
#else
__device__ __forceinline__ float fast_exp2(float x) { return exp2f(x); }
#endif
#if __has_builtin(__builtin_amdgcn_rcpf)
__device__ __forceinline__ float fast_rcp(float x) { return __builtin_amdgcn_rcpf(x); }
#else
__device__ __forceinline__ float fast_rcp(float x) { return 1.0f / x; }
#endif

// LDS-only waits: lgkmcnt(0), vmcnt/expcnt unconstrained (imm 0xc07f, gfx9).
__device__ __forceinline__ void sync_lds() {
  __builtin_amdgcn_s_waitcnt(0xc07f);
  __builtin_amdgcn_s_barrier();
}

// ---------------------------------------------------------------------------
// pad w_ih_l0 f32 [512,100] -> bf16 [2][512][128], rows scaled by gate factor
__global__ void padw_kernel(const float* __restrict__ w0, const float* __restrict__ w1,
                            u16* __restrict__ out) {
  int idx = blockIdx.x * 256 + threadIdx.x;  // 131072
  int d = idx >> 16;
  int n = (idx >> 7) & 511;
  int k = idx & 127;
  float sc = ((n >> 7) == 2) ? L2E2 : L2E;
  const float* w = d ? w1 : w0;
  out[idx] = (k < 100) ? f2bf(w[n * 100 + k] * sc) : (u16)0;
}

// fused f32->bf16 convert for 6 weight arrays, rows scaled by gate factor.
__global__ void cvt6_kernel(const float* s0, const float* s1, const float* s2,
                            const float* s3, const float* s4, const float* s5,
                            u16* d0, u16* d1, u16* d2, u16* d3, u16* d4, u16* d5,
                            int n0, int n1, int n2, int n3, int n4, int n5) {
  int y = blockIdx.y;
  const float* s; u16* d; int n; int gs;
  switch (y) {
    case 0: s = s0; d = d0; n = n0; gs = 14; break;
    case 1: s = s1; d = d1; n = n1; gs = 14; break;
    case 2: s = s2; d = d2; n = n2; gs = 14; break;
    case 3: s = s3; d = d3; n = n3; gs = 14; break;
    case 4: s = s4; d = d4; n = n4; gs = 15; break;
    default: s = s5; d = d5; n = n5; gs = 15; break;
  }
  int i = blockIdx.x * 256 + threadIdx.x;
  if (i < n) {
    float sc = (((i >> gs) & 3) == 2) ? L2E2 : L2E;
    d[i] = f2bf(s[i] * sc);
  }
}

// ---------------------------------------------------------------------------
// Fused kernel. Blocks 0..31: lstm chunk `lc` (8 batch rows each, 2 dirs x
// 16 wg). Blocks 32..1055: proj chunk `pc`.
// xpc layout: [dir*16+wg][sl][colgrp8][gate4][lane64-as-u32][rr2] u16
//             (8KB step tiles; one dword per lane per gate per step).
template <int PK, int LL>
__global__ __launch_bounds__(512, 2) void fused_chunk(
    int do_lstm, int lc, int pc,
    const float* __restrict__ Aemb, const u16* __restrict__ Ah,
    const int* __restrict__ X,
    const u16* __restrict__ W0, const u16* __restrict__ W1,   // [512][PK] bf16
    const float* __restrict__ bih0, const float* __restrict__ bhh0,
    const float* __restrict__ bih1, const float* __restrict__ bhh1,
    u16* __restrict__ xpc0, u16* __restrict__ xpc1,           // double buffer
    const u16* __restrict__ WHH0, const u16* __restrict__ WHH1,
    u16* __restrict__ OUT, float* __restrict__ FINALS,
    u16* __restrict__ HS, float* __restrict__ CS)
{
  // smem: proj As(18432)+Bs(18432)+toks(512)=37376; lstm hb(8704)
  __shared__ __align__(16) unsigned char smem[37888];

  const int tid = threadIdx.x;
  const int lane = tid & 63, wv = tid >> 6;
  const int l15 = lane & 15, q = lane >> 4;

  if (blockIdx.x >= 32) {
    // ------------------------- proj part (8 waves, 64x32 wave tiles) -------
    constexpr int BK = 64;
    constexpr int LDA = 72;
    constexpr bool GATHER = (PK == 128);
    u16* As = (u16*)smem;
    u16* Bs = As + 128 * LDA;
    int* toks = (int*)(Bs + 128 * LDA);

    const int pb = blockIdx.x - 32;
    const int b = pb & 127;
    const int gate = (pb >> 7) & 3;
    const int nt0 = gate * 128;
    const int dir = pb >> 9;
    const u16* W = dir ? W1 : W0;
    u16* XPC = (pc & 1) ? xpc1 : xpc0;

    const int wr = wv >> 2, wc = wv & 3;   // 2 x 4 waves

    if (GATHER) {
      if (tid < 128) {
        int t = dir ? (NT - 1 - pc * TC - tid) : (pc * TC + tid);
        toks[tid] = X[b * NT + t];
      }
    }

    f32x4 acc[4][2];
#pragma unroll
    for (int a = 0; a < 4; a++)
#pragma unroll
      for (int bb = 0; bb < 2; bb++)
        acc[a][bb] = (f32x4){0.f, 0.f, 0.f, 0.f};

    const int srow = tid >> 3;        // 0..63
    const int sseg = (tid & 7) * 8;   // 0..56

    for (int k0 = 0; k0 < PK; k0 += BK) {
      __syncthreads();   // also covers toks on first iteration
#pragma unroll
      for (int p = 0; p < 2; p++) {
        int row = srow + p * 64;
        if (GATHER) {
          int tok = toks[row];
          const float* er = Aemb + (size_t)tok * 100;
          int kb = k0 + sseg;
          union { ushort8v v; u16 e[8]; } tu;
          if (kb + 8 <= 100) {
            f32x4 a0 = *(const f32x4*)&er[kb];
            f32x4 a1 = *(const f32x4*)&er[kb + 4];
#pragma unroll
            for (int j = 0; j < 4; j++) { tu.e[j] = f2bf(a0[j]); tu.e[4 + j] = f2bf(a1[j]); }
          } else {
#pragma unroll
            for (int j = 0; j < 8; j++) tu.e[j] = (kb + j < 100) ? f2bf(er[kb + j]) : (u16)0;
          }
          *(ushort8v*)&As[row * LDA + sseg] = tu.v;
        } else {
          int t = dir ? (NT - 1 - pc * TC - row) : (pc * TC + row);
          const u16* srcA = Ah + (size_t)(b * NT + t) * PK + k0 + sseg;
          *(ushort8v*)&As[row * LDA + sseg] = *(const ushort8v*)srcA;
        }
        const u16* srcB = W + (size_t)(nt0 + row) * PK + k0 + sseg;
        *(ushort8v*)&Bs[row * LDA + sseg] = *(const ushort8v*)srcB;
      }
      __syncthreads();
#pragma unroll
      for (int kk = 0; kk < BK; kk += 32) {
        bf16x8 af[4], bfr[2];
#pragma unroll
        for (int mt = 0; mt < 4; mt++)
          af[mt] = *(const bf16x8*)&As[(wr * 64 + mt * 16 + l15) * LDA + kk + q * 8];
#pragma unroll
        for (int nt = 0; nt < 2; nt++)
          bfr[nt] = *(const bf16x8*)&Bs[(wc * 32 + nt * 16 + l15) * LDA + kk + q * 8];
#pragma unroll
        for (int mt = 0; mt < 4; mt++)
#pragma unroll
          for (int nt = 0; nt < 2; nt++)
            acc[mt][nt] = __builtin_amdgcn_mfma_f32_16x16x32_bf16(af[mt], bfr[nt], acc[mt][nt], 0, 0, 0);
      }
    }

    const float* bih = dir ? bih1 : bih0;
    const float* bhh = dir ? bhh1 : bhh0;
    const float gsc = (gate == 2) ? L2E2 : L2E;
    // xpc dest for value (sl, row=b&7, gate, col):
    //   u16 off = sl*4096 + (col>>4)*512 + gate*128 + (col&15)*2
    //           + ((rb>>1)&1)*64 + ((rb>>2)&1)*32 + (rb&1)
    const int rb = b & 7;
    u16* xo = XPC + (size_t)(dir * 16 + (b >> 3)) * TC * 4096
                  + ((rb >> 1) & 1) * 64 + ((rb >> 2) & 1) * 32 + (rb & 1) + l15 * 2;
#pragma unroll
    for (int nt = 0; nt < 2; nt++) {
      int col = wc * 32 + nt * 16 + l15;          // within-gate col 0..127
      int n = nt0 + col;
      float bias = (bih[n] + bhh[n]) * gsc;
      int bnt = ((wc * 2 + nt) * 4 + gate) * 128;
#pragma unroll
      for (int mt = 0; mt < 4; mt++) {
        int slb = wr * 64 + mt * 16 + q * 4;   // step-local index base
#pragma unroll
        for (int r = 0; r < 4; r++)
          xo[(size_t)(slb + r) * 4096 + bnt] = f2bf(acc[mt][nt][r] + bias);
      }
    }
    return;
  }

  // -------------- lstm part (8 rows/WG, dup-row reg-select remap) ----------
  if (!do_lstm) return;

  __builtin_amdgcn_s_setprio(3);

  const int wg = blockIdx.x & 15, dir = blockIdx.x >> 4;
  const int hc = 16 * wv + l15;
  const u16* XPC = (lc & 1) ? xpc1 : xpc0;

  // lane row ownership: rows {row0, row0+1}, col hc
  // q=0 -> {0,1}, q=1 -> {4,5}, q=2 -> {2,3}, q=3 -> {6,7}
  const int row0 = ((lane >> 4) & 1) * 4 + (lane >> 5) * 2;

  const u16* Wp = dir ? WHH1 : WHH0;
  bf16x8 wf[4][4];
#pragma unroll
  for (int gi = 0; gi < 4; gi++)
#pragma unroll
    for (int kt = 0; kt < 4; kt++)
      wf[gi][kt] = *(const bf16x8*)&Wp[(gi * 128 + hc) * 128 + kt * 32 + q * 8];

  u16* hb = (u16*)smem;   // [2][16*136] u16; rows 8..15 duplicate rows 0..7

  const int g0 = (dir * 128 + wg * 8 + row0) * 128 + hc;  // HS/CS row0 slot
  f32x2 cst2;
  if (lc == 0) {
    for (int i = tid; i < 2 * 16 * 136; i += 512) hb[i] = 0;
    cst2 = (f32x2){0.f, 0.f};
  } else {
    // restore plane 0: rows 0..7 + dup rows 8..15 (each lane: 2 rows, col hc)
    u16 h0 = HS[g0], h1 = HS[g0 + 128];
    hb[row0 * 136 + hc] = h0;
    hb[(row0 + 1) * 136 + hc] = h1;
    hb[(row0 + 8) * 136 + hc] = h0;
    hb[(row0 + 9) * 136 + hc] = h1;
    cst2[0] = CS[g0];
    cst2[1] = CS[g0 + 128];
    // plane 1 needs no init: every step writes all 16 rows of the next plane
  }

  // xp lane base: one dword per gate per step at (colgrp=wv, gate, lane)
  const u16* xb = XPC + (size_t)(dir * 16 + wg) * TC * 4096 + wv * 512 + lane * 2;

#define LDXP(dst, s) do {                                        \
    const u16* nb_ = xb + (size_t)(s) * 4096;                    \
    _Pragma("unroll")                                            \
    for (int gi_ = 0; gi_ < 4; gi_++)                            \
      (dst)[gi_] = *(const unsigned int*)(nb_ + gi_ * 128);      \
  } while (0)

  // depth-2 prefetch: 4 rotating dword[4] buffers, static indexing
  unsigned int xp[4][4];
  LDXP(xp[0], 0);
  LDXP(xp[1], 1);

  const int t0 = dir ? (NT - 1 - lc * TC) : (lc * TC);
  const int tstep = dir ? -256 : 256;
  u16* optr[2];
  if (LL == 0) {
#pragma unroll
    for (int rr = 0; rr < 2; rr++)
      optr[rr] = OUT + ((size_t)(wg * 8 + row0 + rr) * NT + t0) * 256 + dir * 128 + hc;
  }

  const f32x4 zero4 = {0.f, 0.f, 0.f, 0.f};
  const bool hi32 = (lane >= 32);

  __syncthreads();

  int p = 0;
#pragma unroll 1
  for (int sl = 0; sl < TC; sl += 4) {
#pragma unroll
    for (int jj = 0; jj < 4; jj++) {
      const int scur = sl + jj;
      const unsigned int* xcur = xp[jj];
      unsigned int* xnxt = xp[(jj + 2) & 3];

      bf16x8 ah[4];
#pragma unroll
      for (int kt = 0; kt < 4; kt++)
        ah[kt] = *(const bf16x8*)&hb[p * 2176 + l15 * 136 + kt * 32 + q * 8];

      // prefetch step scur+2 (clamped: harmless re-read near chunk end)
      {
        int sn = scur + 2; if (sn > TC - 1) sn = TC - 1;
        LDXP(xnxt, sn);
      }

      // MFMA with zero C-init (xp added after remap)
      f32x4 acc[4];
#pragma unroll
      for (int gi = 0; gi < 4; gi++) {
        acc[gi] = __builtin_amdgcn_mfma_f32_16x16x32_bf16(ah[0], wf[gi][0], zero4, 0, 0, 0);
#pragma unroll
        for (int kt = 1; kt < 4; kt++)
          acc[gi] = __builtin_amdgcn_mfma_f32_16x16x32_bf16(ah[kt], wf[gi][kt], acc[gi], 0, 0, 0);
      }

      // dup-row remap: A rows 8..15 duplicate 0..7, so lane(l15,q) reg r =
      // batch row (4q+r) mod 8. Ownership row0={0,4,2,6}[q] -> regs {0,1}
      // for lanes<32, regs {2,3} for lanes>=32. Pure register select.
      f32x2 ar[4];
#pragma unroll
      for (int gi = 0; gi < 4; gi++) {
        ar[gi][0] = hi32 ? acc[gi][2] : acc[gi][0];
        ar[gi][1] = hi32 ? acc[gi][3] : acc[gi][1];
      }

      // unpack xp dwords -> f32x2 over rr (rr0 -> <<16, rr1 -> mask)
      f32x2 xv[4];
#pragma unroll
      for (int gi = 0; gi < 4; gi++) {
        union { unsigned int u; float f; } lo, hi;
        lo.u = xcur[gi] << 16;
        hi.u = xcur[gi] & 0xFFFF0000u;
        xv[gi][0] = lo.f; xv[gi][1] = hi.f;
      }

      // packed gate math (rr = vector lane). Preacts pre-scaled by L2E/L2E2.
      f32x2 pi = ar[0] + xv[0];
      f32x2 pf = ar[1] + xv[1];
      f32x2 pg = ar[2] + xv[2];
      f32x2 po = ar[3] + xv[3];
      f32x2 ei, ef, eg, eo;
      ei[0] = fast_exp2(pi[0]); ei[1] = fast_exp2(pi[1]);
      ef[0] = fast_exp2(pf[0]); ef[1] = fast_exp2(pf[1]);
      eg[0] = fast_exp2(pg[0]); eg[1] = fast_exp2(pg[1]);
      eo[0] = fast_exp2(po[0]); eo[1] = fast_exp2(po[1]);
      f32x2 A  = 1.f + ef;
      f32x2 Bv = 1.f + ei;
      f32x2 Cg = 1.f + eg;
      f32x2 BC = Bv * Cg;
      f32x2 num = cst2 * ef * BC + ei * (eg - 1.f) * A;
      f32x2 den = A * BC;
      f32x2 rden; rden[0] = fast_rcp(den[0]); rden[1] = fast_rcp(den[1]);
      f32x2 cn = num * rden;
      cst2 = cn;
      f32x2 tc2 = L2E2 * cn;
      f32x2 ec; ec[0] = fast_exp2(tc2[0]); ec[1] = fast_exp2(tc2[1]);
      f32x2 d2 = (1.f + eo) * (1.f + ec);
      f32x2 r2; r2[0] = fast_rcp(d2[0]); r2[1] = fast_rcp(d2[1]);
      f32x2 hv2 = eo * (ec - 1.f) * r2;

      u16 hbv0 = f2bf(hv2[0]);
      u16 hbv1 = f2bf(hv2[1]);
      u16* hn = hb + (p ^ 1) * 2176;
      hn[row0 * 136 + hc] = hbv0;
      hn[(row0 + 1) * 136 + hc] = hbv1;
      hn[(row0 + 8) * 136 + hc] = hbv0;     // dup half (off-chain)
      hn[(row0 + 9) * 136 + hc] = hbv1;
      if (LL == 0) {
        *optr[0] = hbv0; optr[0] += tstep;
        *optr[1] = hbv1; optr[1] += tstep;
      }
      if (scur == TC - 1) {
        HS[g0] = hbv0;
        HS[g0 + 128] = hbv1;
        CS[g0] = cst2[0];
        CS[g0 + 128] = cst2[1];
        if (LL == 1 && lc == NCHUNK - 1) {
          FINALS[(wg * 8 + row0) * 256 + dir * 128 + hc] = hv2[0];
          FINALS[(wg * 8 + row0 + 1) * 256 + dir * 128 + hc] = hv2[1];
        }
      }
      sync_lds();   // h-exchange: lgkmcnt(0)+barrier; VMEM stays in flight
      p ^= 1;
    }
  }
#undef LDXP
}

// ---------------------------------------------------------------------------
// fc: out[b][c] = finals[b][:] . fc_w[c][:] + fc_b[c]  (all f32)
__global__ void fc_kernel(const float* __restrict__ finals, const float* __restrict__ fcw,
                          const float* __restrict__ fcb, float* __restrict__ out) {
  int tid = threadIdx.x;  // 256 = 128 b x 2 c
  int b = tid >> 1, cc = tid & 1;
  float s = fcb[cc];
  for (int k = 0; k < 256; k++) s += finals[b * 256 + k] * fcw[cc * 256 + k];
  out[b * 2 + cc] = s;
}

// ---------------------------------------------------------------------------
extern "C" void kernel_launch(void* const* d_in, const int* in_sizes, int n_in,
                              void* d_out, int out_size, void* d_ws, size_t ws_size,
                              hipStream_t stream) {
  const int*   x        = (const int*)d_in[0];
  const float* emb      = (const float*)d_in[1];
  const float* w_ih_l0  = (const float*)d_in[2];
  const float* w_hh_l0  = (const float*)d_in[3];
  const float* b_ih_l0  = (const float*)d_in[4];
  const float* b_hh_l0  = (const float*)d_in[5];
  const float* w_ih_l0r = (const float*)d_in[6];
  const float* w_hh_l0r = (const float*)d_in[7];
  const float* b_ih_l0r = (const float*)d_in[8];
  const float* b_hh_l0r = (const float*)d_in[9];
  const float* w_ih_l1  = (const float*)d_in[10];
  const float* w_hh_l1  = (const float*)d_in[11];
  const float* b_ih_l1  = (const float*)d_in[12];
  const float* b_hh_l1  = (const float*)d_in[13];
  const float* w_ih_l1r = (const float*)d_in[14];
  const float* w_hh_l1r = (const float*)d_in[15];
  const float* b_ih_l1r = (const float*)d_in[16];
  const float* b_hh_l1r = (const float*)d_in[17];
  const float* fc_w     = (const float*)d_in[18];
  const float* fc_b     = (const float*)d_in[19];
  float* out = (float*)d_out;

  // workspace layout — total 135,856,128 B (r8-r19 footprint, proven)
  char* ws = (char*)d_ws;
  size_t off = 0;
  u16*   h1cat = (u16*)(ws + off);   off += 67108864;  // [NB*NT][256] bf16
  u16*   xpc0  = (u16*)(ws + off);   off += 33554432;  // xp double buffer 0
  u16*   xpc1  = (u16*)(ws + off);   off += 33554432;  // xp double buffer 1
  u16*   w0pad = (u16*)(ws + off);   off += 262144;    // [2][512][128] bf16 (scaled)
  u16*   wih1b = (u16*)(ws + off);   off += 524288;    // [2][512][256] bf16 (scaled)
  u16*   whhb  = (u16*)(ws + off);   off += 524288;    // [4][512][128] bf16 (scaled)
  u16*   hs    = (u16*)(ws + off);   off += 65536;     // [2][128][128] bf16
  float* cs    = (float*)(ws + off); off += 131072;    // [2][128][128] f32
  float* fin   = (float*)(ws + off); off += 131072;    // [128][256] f32
  if (ws_size < off) return;  // constant across calls -> same work every call

  hipLaunchKernelGGL(padw_kernel, dim3(512), dim3(256), 0, stream,
                     w_ih_l0, w_ih_l0r, w0pad);
  hipLaunchKernelGGL(cvt6_kernel, dim3(512, 6), dim3(256), 0, stream,
                     w_hh_l0, w_hh_l0r, w_hh_l1, w_hh_l1r, w_ih_l1, w_ih_l1r,
                     whhb, whhb + 65536, whhb + 131072, whhb + 196608,
                     wih1b, wih1b + 131072,
                     65536, 65536, 65536, 65536, 131072, 131072);

  // Layer 0: launch k does proj0(k) [k<8] fused with lstm0(k-1) [k>0]
  for (int k = 0; k <= NCHUNK; k++) {
    int do_proj = (k < NCHUNK);
    int do_lstm = (k > 0);
    hipLaunchKernelGGL((fused_chunk<128, 0>), dim3(do_proj ? 1056 : 32), dim3(512), 0, stream,
                       do_lstm, k - 1, k,
                       emb, (const u16*)nullptr, x, w0pad, w0pad + 65536,
                       b_ih_l0, b_hh_l0, b_ih_l0r, b_hh_l0r,
                       xpc0, xpc1, whhb, whhb + 65536,
                       h1cat, fin, hs, cs);
  }
  // Layer 1: same pattern, proj reads h1cat (complete after layer-0 phase)
  for (int k = 0; k <= NCHUNK; k++) {
    int do_proj = (k < NCHUNK);
    int do_lstm = (k > 0);
    hipLaunchKernelGGL((fused_chunk<256, 1>), dim3(do_proj ? 1056 : 32), dim3(512), 0, stream,
                       do_lstm, k - 1, k,
                       (const float*)nullptr, h1cat, (const int*)nullptr,
                       wih1b, wih1b + 131072,
                       b_ih_l1, b_hh_l1, b_ih_l1r, b_hh_l1r,
                       xpc0, xpc1, whhb + 131072, whhb + 196608,
                       h1cat, fin, hs, cs);
  }
  hipLaunchKernelGGL(fc_kernel, dim3(1), dim3(256), 0, stream, fin, fc_w, fc_b, out);
}

// Round 9
// 1463.132 us; speedup vs baseline: 1.9123x; 1.0042x over previous
//
#include <hip/hip_runtime.h>
#include <hip/hip_bf16.h>
#include <stdint.h>

// ---------------------------------------------------------------------------
// BiLSTM classifier: V=50000 E=100 H=128 B=128 T=1024 C=2. f32 I/O.
// Round 21 = r20 + LDS occupancy squeeze (dynamic smem 54656B). Model (2
// predictive hits r19/r20): step time ~ chain-instr x waves-per-SIMD issue
// interleave + fixed latencies. lstm CU currently hosts 1 lstm + ~3 proj
// blocks = ~8 waves/SIMD -> ~20cyc/chain-instr. 54656B x 3 > 160KB forces
// <=2 blocks/CU: lstm CU = lstm + 1 proj = 4 waves/SIMD -> ~halves the
// interleave term. Proj slack (MfmaUtil 5.5%, HBM 15%) absorbs the slot loss
// (~850 -> ~480 concurrent proj blocks). Everything else identical to r20
// (dup-row reg-select remap, depth-2 xp prefetch, packed gates).
// ---------------------------------------------------------------------------

typedef unsigned short u16;
typedef short bf16x8 __attribute__((ext_vector_type(8)));
typedef unsigned short ushort8v __attribute__((ext_vector_type(8)));
typedef float f32x4 __attribute__((ext_vector_type(4)));
typedef float f32x2 __attribute__((ext_vector_type(2)));

#define NB 128
#define NT 1024
#define NH 128
#define TC 128         // chunk length (steps)
#define NCHUNK (NT / TC)
#define SMEM_BYTES 54656   // 3x > 160KB -> max 2 blocks/CU

#define L2E  1.44269504088896f
#define L2E2 2.88539008177793f

__device__ __forceinline__ u16 f2bf(float f) {
  union { float f; unsigned int i; } v; v.f = f;
  unsigned int i = v.i;
  return (u16)((i + 0x7FFFu + ((i >> 16) & 1u)) >> 16);  // RNE
}

#if __has_builtin(__builtin_amdgcn_exp2f)
__device__ __forceinline__ float fast_exp2(float x) { return __builtin_amdgcn_exp2f(x); }
#else
__device__ __forceinline__ float fast_exp2(float x) { return exp2f(x); }
#endif
#if __has_builtin(__builtin_amdgcn_rcpf)
__device__ __forceinline__ float fast_rcp(float x) { return __builtin_amdgcn_rcpf(x); }
#else
__device__ __forceinline__ float fast_rcp(float x) { return 1.0f / x; }
#endif

// LDS-only waits: lgkmcnt(0), vmcnt/expcnt unconstrained (imm 0xc07f, gfx9).
__device__ __forceinline__ void sync_lds() {
  __builtin_amdgcn_s_waitcnt(0xc07f);
  __builtin_amdgcn_s_barrier();
}

// ---------------------------------------------------------------------------
// pad w_ih_l0 f32 [512,100] -> bf16 [2][512][128], rows scaled by gate factor
__global__ void padw_kernel(const float* __restrict__ w0, const float* __restrict__ w1,
                            u16* __restrict__ out) {
  int idx = blockIdx.x * 256 + threadIdx.x;  // 131072
  int d = idx >> 16;
  int n = (idx >> 7) & 511;
  int k = idx & 127;
  float sc = ((n >> 7) == 2) ? L2E2 : L2E;
  const float* w = d ? w1 : w0;
  out[idx] = (k < 100) ? f2bf(w[n * 100 + k] * sc) : (u16)0;
}

// fused f32->bf16 convert for 6 weight arrays, rows scaled by gate factor.
__global__ void cvt6_kernel(const float* s0, const float* s1, const float* s2,
                            const float* s3, const float* s4, const float* s5,
                            u16* d0, u16* d1, u16* d2, u16* d3, u16* d4, u16* d5,
                            int n0, int n1, int n2, int n3, int n4, int n5) {
  int y = blockIdx.y;
  const float* s; u16* d; int n; int gs;
  switch (y) {
    case 0: s = s0; d = d0; n = n0; gs = 14; break;
    case 1: s = s1; d = d1; n = n1; gs = 14; break;
    case 2: s = s2; d = d2; n = n2; gs = 14; break;
    case 3: s = s3; d = d3; n = n3; gs = 14; break;
    case 4: s = s4; d = d4; n = n4; gs = 15; break;
    default: s = s5; d = d5; n = n5; gs = 15; break;
  }
  int i = blockIdx.x * 256 + threadIdx.x;
  if (i < n) {
    float sc = (((i >> gs) & 3) == 2) ? L2E2 : L2E;
    d[i] = f2bf(s[i] * sc);
  }
}

// ---------------------------------------------------------------------------
// Fused kernel. Blocks 0..31: lstm chunk `lc` (8 batch rows each, 2 dirs x
// 16 wg). Blocks 32..1055: proj chunk `pc`.
// xpc layout: [dir*16+wg][sl][colgrp8][gate4][lane64-as-u32][rr2] u16
//             (8KB step tiles; one dword per lane per gate per step).
template <int PK, int LL>
__global__ __launch_bounds__(512, 2) void fused_chunk(
    int do_lstm, int lc, int pc,
    const float* __restrict__ Aemb, const u16* __restrict__ Ah,
    const int* __restrict__ X,
    const u16* __restrict__ W0, const u16* __restrict__ W1,   // [512][PK] bf16
    const float* __restrict__ bih0, const float* __restrict__ bhh0,
    const float* __restrict__ bih1, const float* __restrict__ bhh1,
    u16* __restrict__ xpc0, u16* __restrict__ xpc1,           // double buffer
    const u16* __restrict__ WHH0, const u16* __restrict__ WHH1,
    u16* __restrict__ OUT, float* __restrict__ FINALS,
    u16* __restrict__ HS, float* __restrict__ CS)
{
  // dynamic smem (54656B requested -> occupancy cap 2 blocks/CU):
  // proj uses As(18432)+Bs(18432)+toks(512)=37376; lstm hb(8704)
  extern __shared__ __align__(16) unsigned char smem[];

  const int tid = threadIdx.x;
  const int lane = tid & 63, wv = tid >> 6;
  const int l15 = lane & 15, q = lane >> 4;

  if (blockIdx.x >= 32) {
    // ------------------------- proj part (8 waves, 64x32 wave tiles) -------
    constexpr int BK = 64;
    constexpr int LDA = 72;
    constexpr bool GATHER = (PK == 128);
    u16* As = (u16*)smem;
    u16* Bs = As + 128 * LDA;
    int* toks = (int*)(Bs + 128 * LDA);

    const int pb = blockIdx.x - 32;
    const int b = pb & 127;
    const int gate = (pb >> 7) & 3;
    const int nt0 = gate * 128;
    const int dir = pb >> 9;
    const u16* W = dir ? W1 : W0;
    u16* XPC = (pc & 1) ? xpc1 : xpc0;

    const int wr = wv >> 2, wc = wv & 3;   // 2 x 4 waves

    if (GATHER) {
      if (tid < 128) {
        int t = dir ? (NT - 1 - pc * TC - tid) : (pc * TC + tid);
        toks[tid] = X[b * NT + t];
      }
    }

    f32x4 acc[4][2];
#pragma unroll
    for (int a = 0; a < 4; a++)
#pragma unroll
      for (int bb = 0; bb < 2; bb++)
        acc[a][bb] = (f32x4){0.f, 0.f, 0.f, 0.f};

    const int srow = tid >> 3;        // 0..63
    const int sseg = (tid & 7) * 8;   // 0..56

    for (int k0 = 0; k0 < PK; k0 += BK) {
      __syncthreads();   // also covers toks on first iteration
#pragma unroll
      for (int p = 0; p < 2; p++) {
        int row = srow + p * 64;
        if (GATHER) {
          int tok = toks[row];
          const float* er = Aemb + (size_t)tok * 100;
          int kb = k0 + sseg;
          union { ushort8v v; u16 e[8]; } tu;
          if (kb + 8 <= 100) {
            f32x4 a0 = *(const f32x4*)&er[kb];
            f32x4 a1 = *(const f32x4*)&er[kb + 4];
#pragma unroll
            for (int j = 0; j < 4; j++) { tu.e[j] = f2bf(a0[j]); tu.e[4 + j] = f2bf(a1[j]); }
          } else {
#pragma unroll
            for (int j = 0; j < 8; j++) tu.e[j] = (kb + j < 100) ? f2bf(er[kb + j]) : (u16)0;
          }
          *(ushort8v*)&As[row * LDA + sseg] = tu.v;
        } else {
          int t = dir ? (NT - 1 - pc * TC - row) : (pc * TC + row);
          const u16* srcA = Ah + (size_t)(b * NT + t) * PK + k0 + sseg;
          *(ushort8v*)&As[row * LDA + sseg] = *(const ushort8v*)srcA;
        }
        const u16* srcB = W + (size_t)(nt0 + row) * PK + k0 + sseg;
        *(ushort8v*)&Bs[row * LDA + sseg] = *(const ushort8v*)srcB;
      }
      __syncthreads();
#pragma unroll
      for (int kk = 0; kk < BK; kk += 32) {
        bf16x8 af[4], bfr[2];
#pragma unroll
        for (int mt = 0; mt < 4; mt++)
          af[mt] = *(const bf16x8*)&As[(wr * 64 + mt * 16 + l15) * LDA + kk + q * 8];
#pragma unroll
        for (int nt = 0; nt < 2; nt++)
          bfr[nt] = *(const bf16x8*)&Bs[(wc * 32 + nt * 16 + l15) * LDA + kk + q * 8];
#pragma unroll
        for (int mt = 0; mt < 4; mt++)
#pragma unroll
          for (int nt = 0; nt < 2; nt++)
            acc[mt][nt] = __builtin_amdgcn_mfma_f32_16x16x32_bf16(af[mt], bfr[nt], acc[mt][nt], 0, 0, 0);
      }
    }

    const float* bih = dir ? bih1 : bih0;
    const float* bhh = dir ? bhh1 : bhh0;
    const float gsc = (gate == 2) ? L2E2 : L2E;
    // xpc dest for value (sl, row=b&7, gate, col):
    //   u16 off = sl*4096 + (col>>4)*512 + gate*128 + (col&15)*2
    //           + ((rb>>1)&1)*64 + ((rb>>2)&1)*32 + (rb&1)
    const int rb = b & 7;
    u16* xo = XPC + (size_t)(dir * 16 + (b >> 3)) * TC * 4096
                  + ((rb >> 1) & 1) * 64 + ((rb >> 2) & 1) * 32 + (rb & 1) + l15 * 2;
#pragma unroll
    for (int nt = 0; nt < 2; nt++) {
      int col = wc * 32 + nt * 16 + l15;          // within-gate col 0..127
      int n = nt0 + col;
      float bias = (bih[n] + bhh[n]) * gsc;
      int bnt = ((wc * 2 + nt) * 4 + gate) * 128;
#pragma unroll
      for (int mt = 0; mt < 4; mt++) {
        int slb = wr * 64 + mt * 16 + q * 4;   // step-local index base
#pragma unroll
        for (int r = 0; r < 4; r++)
          xo[(size_t)(slb + r) * 4096 + bnt] = f2bf(acc[mt][nt][r] + bias);
      }
    }
    return;
  }

  // -------------- lstm part (8 rows/WG, dup-row reg-select remap) ----------
  if (!do_lstm) return;

  __builtin_amdgcn_s_setprio(3);

  const int wg = blockIdx.x & 15, dir = blockIdx.x >> 4;
  const int hc = 16 * wv + l15;
  const u16* XPC = (lc & 1) ? xpc1 : xpc0;

  // lane row ownership: rows {row0, row0+1}, col hc
  // q=0 -> {0,1}, q=1 -> {4,5}, q=2 -> {2,3}, q=3 -> {6,7}
  const int row0 = ((lane >> 4) & 1) * 4 + (lane >> 5) * 2;

  const u16* Wp = dir ? WHH1 : WHH0;
  bf16x8 wf[4][4];
#pragma unroll
  for (int gi = 0; gi < 4; gi++)
#pragma unroll
    for (int kt = 0; kt < 4; kt++)
      wf[gi][kt] = *(const bf16x8*)&Wp[(gi * 128 + hc) * 128 + kt * 32 + q * 8];

  u16* hb = (u16*)smem;   // [2][16*136] u16; rows 8..15 duplicate rows 0..7

  const int g0 = (dir * 128 + wg * 8 + row0) * 128 + hc;  // HS/CS row0 slot
  f32x2 cst2;
  if (lc == 0) {
    for (int i = tid; i < 2 * 16 * 136; i += 512) hb[i] = 0;
    cst2 = (f32x2){0.f, 0.f};
  } else {
    // restore plane 0: rows 0..7 + dup rows 8..15 (each lane: 2 rows, col hc)
    u16 h0 = HS[g0], h1 = HS[g0 + 128];
    hb[row0 * 136 + hc] = h0;
    hb[(row0 + 1) * 136 + hc] = h1;
    hb[(row0 + 8) * 136 + hc] = h0;
    hb[(row0 + 9) * 136 + hc] = h1;
    cst2[0] = CS[g0];
    cst2[1] = CS[g0 + 128];
    // plane 1 needs no init: every step writes all 16 rows of the next plane
  }

  // xp lane base: one dword per gate per step at (colgrp=wv, gate, lane)
  const u16* xb = XPC + (size_t)(dir * 16 + wg) * TC * 4096 + wv * 512 + lane * 2;

#define LDXP(dst, s) do {                                        \
    const u16* nb_ = xb + (size_t)(s) * 4096;                    \
    _Pragma("unroll")                                            \
    for (int gi_ = 0; gi_ < 4; gi_++)                            \
      (dst)[gi_] = *(const unsigned int*)(nb_ + gi_ * 128);      \
  } while (0)

  // depth-2 prefetch: 4 rotating dword[4] buffers, static indexing
  unsigned int xp[4][4];
  LDXP(xp[0], 0);
  LDXP(xp[1], 1);

  const int t0 = dir ? (NT - 1 - lc * TC) : (lc * TC);
  const int tstep = dir ? -256 : 256;
  u16* optr[2];
  if (LL == 0) {
#pragma unroll
    for (int rr = 0; rr < 2; rr++)
      optr[rr] = OUT + ((size_t)(wg * 8 + row0 + rr) * NT + t0) * 256 + dir * 128 + hc;
  }

  const f32x4 zero4 = {0.f, 0.f, 0.f, 0.f};
  const bool hi32 = (lane >= 32);

  __syncthreads();

  int p = 0;
#pragma unroll 1
  for (int sl = 0; sl < TC; sl += 4) {
#pragma unroll
    for (int jj = 0; jj < 4; jj++) {
      const int scur = sl + jj;
      const unsigned int* xcur = xp[jj];
      unsigned int* xnxt = xp[(jj + 2) & 3];

      bf16x8 ah[4];
#pragma unroll
      for (int kt = 0; kt < 4; kt++)
        ah[kt] = *(const bf16x8*)&hb[p * 2176 + l15 * 136 + kt * 32 + q * 8];

      // prefetch step scur+2 (clamped: harmless re-read near chunk end)
      {
        int sn = scur + 2; if (sn > TC - 1) sn = TC - 1;
        LDXP(xnxt, sn);
      }

      // MFMA with zero C-init (xp added after remap)
      f32x4 acc[4];
#pragma unroll
      for (int gi = 0; gi < 4; gi++) {
        acc[gi] = __builtin_amdgcn_mfma_f32_16x16x32_bf16(ah[0], wf[gi][0], zero4, 0, 0, 0);
#pragma unroll
        for (int kt = 1; kt < 4; kt++)
          acc[gi] = __builtin_amdgcn_mfma_f32_16x16x32_bf16(ah[kt], wf[gi][kt], acc[gi], 0, 0, 0);
      }

      // dup-row remap: A rows 8..15 duplicate 0..7, so lane(l15,q) reg r =
      // batch row (4q+r) mod 8. Ownership row0={0,4,2,6}[q] -> regs {0,1}
      // for lanes<32, regs {2,3} for lanes>=32. Pure register select.
      f32x2 ar[4];
#pragma unroll
      for (int gi = 0; gi < 4; gi++) {
        ar[gi][0] = hi32 ? acc[gi][2] : acc[gi][0];
        ar[gi][1] = hi32 ? acc[gi][3] : acc[gi][1];
      }

      // unpack xp dwords -> f32x2 over rr (rr0 -> <<16, rr1 -> mask)
      f32x2 xv[4];
#pragma unroll
      for (int gi = 0; gi < 4; gi++) {
        union { unsigned int u; float f; } lo, hi;
        lo.u = xcur[gi] << 16;
        hi.u = xcur[gi] & 0xFFFF0000u;
        xv[gi][0] = lo.f; xv[gi][1] = hi.f;
      }

      // packed gate math (rr = vector lane). Preacts pre-scaled by L2E/L2E2.
      f32x2 pi = ar[0] + xv[0];
      f32x2 pf = ar[1] + xv[1];
      f32x2 pg = ar[2] + xv[2];
      f32x2 po = ar[3] + xv[3];
      f32x2 ei, ef, eg, eo;
      ei[0] = fast_exp2(pi[0]); ei[1] = fast_exp2(pi[1]);
      ef[0] = fast_exp2(pf[0]); ef[1] = fast_exp2(pf[1]);
      eg[0] = fast_exp2(pg[0]); eg[1] = fast_exp2(pg[1]);
      eo[0] = fast_exp2(po[0]); eo[1] = fast_exp2(po[1]);
      f32x2 A  = 1.f + ef;
      f32x2 Bv = 1.f + ei;
      f32x2 Cg = 1.f + eg;
      f32x2 BC = Bv * Cg;
      f32x2 num = cst2 * ef * BC + ei * (eg - 1.f) * A;
      f32x2 den = A * BC;
      f32x2 rden; rden[0] = fast_rcp(den[0]); rden[1] = fast_rcp(den[1]);
      f32x2 cn = num * rden;
      cst2 = cn;
      f32x2 tc2 = L2E2 * cn;
      f32x2 ec; ec[0] = fast_exp2(tc2[0]); ec[1] = fast_exp2(tc2[1]);
      f32x2 d2 = (1.f + eo) * (1.f + ec);
      f32x2 r2; r2[0] = fast_rcp(d2[0]); r2[1] = fast_rcp(d2[1]);
      f32x2 hv2 = eo * (ec - 1.f) * r2;

      u16 hbv0 = f2bf(hv2[0]);
      u16 hbv1 = f2bf(hv2[1]);
      u16* hn = hb + (p ^ 1) * 2176;
      hn[row0 * 136 + hc] = hbv0;
      hn[(row0 + 1) * 136 + hc] = hbv1;
      hn[(row0 + 8) * 136 + hc] = hbv0;     // dup half (off-chain)
      hn[(row0 + 9) * 136 + hc] = hbv1;
      if (LL == 0) {
        *optr[0] = hbv0; optr[0] += tstep;
        *optr[1] = hbv1; optr[1] += tstep;
      }
      if (scur == TC - 1) {
        HS[g0] = hbv0;
        HS[g0 + 128] = hbv1;
        CS[g0] = cst2[0];
        CS[g0 + 128] = cst2[1];
        if (LL == 1 && lc == NCHUNK - 1) {
          FINALS[(wg * 8 + row0) * 256 + dir * 128 + hc] = hv2[0];
          FINALS[(wg * 8 + row0 + 1) * 256 + dir * 128 + hc] = hv2[1];
        }
      }
      sync_lds();   // h-exchange: lgkmcnt(0)+barrier; VMEM stays in flight
      p ^= 1;
    }
  }
#undef LDXP
}

// ---------------------------------------------------------------------------
// fc: out[b][c] = finals[b][:] . fc_w[c][:] + fc_b[c]  (all f32)
__global__ void fc_kernel(const float* __restrict__ finals, const float* __restrict__ fcw,
                          const float* __restrict__ fcb, float* __restrict__ out) {
  int tid = threadIdx.x;  // 256 = 128 b x 2 c
  int b = tid >> 1, cc = tid & 1;
  float s = fcb[cc];
  for (int k = 0; k < 256; k++) s += finals[b * 256 + k] * fcw[cc * 256 + k];
  out[b * 2 + cc] = s;
}

// ---------------------------------------------------------------------------
extern "C" void kernel_launch(void* const* d_in, const int* in_sizes, int n_in,
                              void* d_out, int out_size, void* d_ws, size_t ws_size,
                              hipStream_t stream) {
  const int*   x        = (const int*)d_in[0];
  const float* emb      = (const float*)d_in[1];
  const float* w_ih_l0  = (const float*)d_in[2];
  const float* w_hh_l0  = (const float*)d_in[3];
  const float* b_ih_l0  = (const float*)d_in[4];
  const float* b_hh_l0  = (const float*)d_in[5];
  const float* w_ih_l0r = (const float*)d_in[6];
  const float* w_hh_l0r = (const float*)d_in[7];
  const float* b_ih_l0r = (const float*)d_in[8];
  const float* b_hh_l0r = (const float*)d_in[9];
  const float* w_ih_l1  = (const float*)d_in[10];
  const float* w_hh_l1  = (const float*)d_in[11];
  const float* b_ih_l1  = (const float*)d_in[12];
  const float* b_hh_l1  = (const float*)d_in[13];
  const float* w_ih_l1r = (const float*)d_in[14];
  const float* w_hh_l1r = (const float*)d_in[15];
  const float* b_ih_l1r = (const float*)d_in[16];
  const float* b_hh_l1r = (const float*)d_in[17];
  const float* fc_w     = (const float*)d_in[18];
  const float* fc_b     = (const float*)d_in[19];
  float* out = (float*)d_out;

  // workspace layout — total 135,856,128 B (r8-r20 footprint, proven)
  char* ws = (char*)d_ws;
  size_t off = 0;
  u16*   h1cat = (u16*)(ws + off);   off += 67108864;  // [NB*NT][256] bf16
  u16*   xpc0  = (u16*)(ws + off);   off += 33554432;  // xp double buffer 0
  u16*   xpc1  = (u16*)(ws + off);   off += 33554432;  // xp double buffer 1
  u16*   w0pad = (u16*)(ws + off);   off += 262144;    // [2][512][128] bf16 (scaled)
  u16*   wih1b = (u16*)(ws + off);   off += 524288;    // [2][512][256] bf16 (scaled)
  u16*   whhb  = (u16*)(ws + off);   off += 524288;    // [4][512][128] bf16 (scaled)
  u16*   hs    = (u16*)(ws + off);   off += 65536;     // [2][128][128] bf16
  float* cs    = (float*)(ws + off); off += 131072;    // [2][128][128] f32
  float* fin   = (float*)(ws + off); off += 131072;    // [128][256] f32
  if (ws_size < off) return;  // constant across calls -> same work every call

  hipLaunchKernelGGL(padw_kernel, dim3(512), dim3(256), 0, stream,
                     w_ih_l0, w_ih_l0r, w0pad);
  hipLaunchKernelGGL(cvt6_kernel, dim3(512, 6), dim3(256), 0, stream,
                     w_hh_l0, w_hh_l0r, w_hh_l1, w_hh_l1r, w_ih_l1, w_ih_l1r,
                     whhb, whhb + 65536, whhb + 131072, whhb + 196608,
                     wih1b, wih1b + 131072,
                     65536, 65536, 65536, 65536, 131072, 131072);

  // Layer 0: launch k does proj0(k) [k<8] fused with lstm0(k-1) [k>0]
  for (int k = 0; k <= NCHUNK; k++) {
    int do_proj = (k < NCHUNK);
    int do_lstm = (k > 0);
    hipLaunchKernelGGL((fused_chunk<128, 0>), dim3(do_proj ? 1056 : 32), dim3(512),
                       SMEM_BYTES, stream,
                       do_lstm, k - 1, k,
                       emb, (const u16*)nullptr, x, w0pad, w0pad + 65536,
                       b_ih_l0, b_hh_l0, b_ih_l0r, b_hh_l0r,
                       xpc0, xpc1, whhb, whhb + 65536,
                       h1cat, fin, hs, cs);
  }
  // Layer 1: same pattern, proj reads h1cat (complete after layer-0 phase)
  for (int k = 0; k <= NCHUNK; k++) {
    int do_proj = (k < NCHUNK);
    int do_lstm = (k > 0);
    hipLaunchKernelGGL((fused_chunk<256, 1>), dim3(do_proj ? 1056 : 32), dim3(512),
                       SMEM_BYTES, stream,
                       do_lstm, k - 1, k,
                       (const float*)nullptr, h1cat, (const int*)nullptr,
                       wih1b, wih1b + 131072,
                       b_ih_l1, b_hh_l1, b_ih_l1r, b_hh_l1r,
                       xpc0, xpc1, whhb + 131072, whhb + 196608,
                       h1cat, fin, hs, cs);
  }
  hipLaunchKernelGGL(fc_kernel, dim3(1), dim3(256), 0, stream, fin, fc_w, fc_b, out);
}

// Round 10
// 1418.153 us; speedup vs baseline: 1.9729x; 1.0317x over previous
//
#include <hip/hip_runtime.h>
#include <hip/hip_bf16.h>
#include <stdint.h>

// ---------------------------------------------------------------------------
// BiLSTM classifier: V=50000 E=100 H=128 B=128 T=1024 C=2. f32 I/O.
// Round 22 = r21 + (1) dup-READ instead of dup-write: ah row addr = (l15&7)
// -> A rows 8..15 alias rows 0..7 in LDS (broadcast reads), dup h-writes and
// zero-guards dropped, hb = [2][8][136]; (2) xp unpack + prefetch issue moved
// to the top of the step so the compiler's vmcnt wait lands right after the
// barrier (loads are 3 steps old there) instead of mid-chain; (3) prefetch
// depth 3. Context: r21 occupancy-squeeze NULL -> step is self-limited
// (~1640cyc); total == 2048 sequential steps x step_time, layers can't
// overlap (bi-dir), so step_time is the only lever.
// ---------------------------------------------------------------------------

typedef unsigned short u16;
typedef short bf16x8 __attribute__((ext_vector_type(8)));
typedef unsigned short ushort8v __attribute__((ext_vector_type(8)));
typedef float f32x4 __attribute__((ext_vector_type(4)));
typedef float f32x2 __attribute__((ext_vector_type(2)));

#define NB 128
#define NT 1024
#define NH 128
#define TC 128         // chunk length (steps)
#define NCHUNK (NT / TC)
#define SMEM_BYTES 54656   // 3x > 160KB -> max 2 blocks/CU (r21, neutral)

#define L2E  1.44269504088896f
#define L2E2 2.88539008177793f

__device__ __forceinline__ u16 f2bf(float f) {
  union { float f; unsigned int i; } v; v.f = f;
  unsigned int i = v.i;
  return (u16)((i + 0x7FFFu + ((i >> 16) & 1u)) >> 16);  // RNE
}

#if __has_builtin(__builtin_amdgcn_exp2f)
__device__ __forceinline__ float fast_exp2(float x) { return __builtin_amdgcn_exp2f(x); }
#else
__device__ __forceinline__ float fast_exp2(float x) { return exp2f(x); }
#endif
#if __has_builtin(__builtin_amdgcn_rcpf)
__device__ __forceinline__ float fast_rcp(float x) { return __builtin_amdgcn_rcpf(x); }
#else
__device__ __forceinline__ float fast_rcp(float x) { return 1.0f / x; }
#endif

// LDS-only waits: lgkmcnt(0), vmcnt/expcnt unconstrained (imm 0xc07f, gfx9).
__device__ __forceinline__ void sync_lds() {
  __builtin_amdgcn_s_waitcnt(0xc07f);
  __builtin_amdgcn_s_barrier();
}

// ---------------------------------------------------------------------------
// pad w_ih_l0 f32 [512,100] -> bf16 [2][512][128], rows scaled by gate factor
__global__ void padw_kernel(const float* __restrict__ w0, const float* __restrict__ w1,
                            u16* __restrict__ out) {
  int idx = blockIdx.x * 256 + threadIdx.x;  // 131072
  int d = idx >> 16;
  int n = (idx >> 7) & 511;
  int k = idx & 127;
  float sc = ((n >> 7) == 2) ? L2E2 : L2E;
  const float* w = d ? w1 : w0;
  out[idx] = (k < 100) ? f2bf(w[n * 100 + k] * sc) : (u16)0;
}

// fused f32->bf16 convert for 6 weight arrays, rows scaled by gate factor.
__global__ void cvt6_kernel(const float* s0, const float* s1, const float* s2,
                            const float* s3, const float* s4, const float* s5,
                            u16* d0, u16* d1, u16* d2, u16* d3, u16* d4, u16* d5,
                            int n0, int n1, int n2, int n3, int n4, int n5) {
  int y = blockIdx.y;
  const float* s; u16* d; int n; int gs;
  switch (y) {
    case 0: s = s0; d = d0; n = n0; gs = 14; break;
    case 1: s = s1; d = d1; n = n1; gs = 14; break;
    case 2: s = s2; d = d2; n = n2; gs = 14; break;
    case 3: s = s3; d = d3; n = n3; gs = 14; break;
    case 4: s = s4; d = d4; n = n4; gs = 15; break;
    default: s = s5; d = d5; n = n5; gs = 15; break;
  }
  int i = blockIdx.x * 256 + threadIdx.x;
  if (i < n) {
    float sc = (((i >> gs) & 3) == 2) ? L2E2 : L2E;
    d[i] = f2bf(s[i] * sc);
  }
}

// ---------------------------------------------------------------------------
// Fused kernel. Blocks 0..31: lstm chunk `lc` (8 batch rows each, 2 dirs x
// 16 wg). Blocks 32..1055: proj chunk `pc`.
// xpc layout: [dir*16+wg][sl][colgrp8][gate4][lane64-as-u32][rr2] u16
//             (8KB step tiles; one dword per lane per gate per step).
template <int PK, int LL>
__global__ __launch_bounds__(512, 2) void fused_chunk(
    int do_lstm, int lc, int pc,
    const float* __restrict__ Aemb, const u16* __restrict__ Ah,
    const int* __restrict__ X,
    const u16* __restrict__ W0, const u16* __restrict__ W1,   // [512][PK] bf16
    const float* __restrict__ bih0, const float* __restrict__ bhh0,
    const float* __restrict__ bih1, const float* __restrict__ bhh1,
    u16* __restrict__ xpc0, u16* __restrict__ xpc1,           // double buffer
    const u16* __restrict__ WHH0, const u16* __restrict__ WHH1,
    u16* __restrict__ OUT, float* __restrict__ FINALS,
    u16* __restrict__ HS, float* __restrict__ CS)
{
  // dynamic smem (54656B requested -> occupancy cap 2 blocks/CU):
  // proj uses As(18432)+Bs(18432)+toks(512)=37376; lstm hb [2][8*136]=4352B
  extern __shared__ __align__(16) unsigned char smem[];

  const int tid = threadIdx.x;
  const int lane = tid & 63, wv = tid >> 6;
  const int l15 = lane & 15, q = lane >> 4;

  if (blockIdx.x >= 32) {
    // ------------------------- proj part (8 waves, 64x32 wave tiles) -------
    constexpr int BK = 64;
    constexpr int LDA = 72;
    constexpr bool GATHER = (PK == 128);
    u16* As = (u16*)smem;
    u16* Bs = As + 128 * LDA;
    int* toks = (int*)(Bs + 128 * LDA);

    const int pb = blockIdx.x - 32;
    const int b = pb & 127;
    const int gate = (pb >> 7) & 3;
    const int nt0 = gate * 128;
    const int dir = pb >> 9;
    const u16* W = dir ? W1 : W0;
    u16* XPC = (pc & 1) ? xpc1 : xpc0;

    const int wr = wv >> 2, wc = wv & 3;   // 2 x 4 waves

    if (GATHER) {
      if (tid < 128) {
        int t = dir ? (NT - 1 - pc * TC - tid) : (pc * TC + tid);
        toks[tid] = X[b * NT + t];
      }
    }

    f32x4 acc[4][2];
#pragma unroll
    for (int a = 0; a < 4; a++)
#pragma unroll
      for (int bb = 0; bb < 2; bb++)
        acc[a][bb] = (f32x4){0.f, 0.f, 0.f, 0.f};

    const int srow = tid >> 3;        // 0..63
    const int sseg = (tid & 7) * 8;   // 0..56

    for (int k0 = 0; k0 < PK; k0 += BK) {
      __syncthreads();   // also covers toks on first iteration
#pragma unroll
      for (int p = 0; p < 2; p++) {
        int row = srow + p * 64;
        if (GATHER) {
          int tok = toks[row];
          const float* er = Aemb + (size_t)tok * 100;
          int kb = k0 + sseg;
          union { ushort8v v; u16 e[8]; } tu;
          if (kb + 8 <= 100) {
            f32x4 a0 = *(const f32x4*)&er[kb];
            f32x4 a1 = *(const f32x4*)&er[kb + 4];
#pragma unroll
            for (int j = 0; j < 4; j++) { tu.e[j] = f2bf(a0[j]); tu.e[4 + j] = f2bf(a1[j]); }
          } else {
#pragma unroll
            for (int j = 0; j < 8; j++) tu.e[j] = (kb + j < 100) ? f2bf(er[kb + j]) : (u16)0;
          }
          *(ushort8v*)&As[row * LDA + sseg] = tu.v;
        } else {
          int t = dir ? (NT - 1 - pc * TC - row) : (pc * TC + row);
          const u16* srcA = Ah + (size_t)(b * NT + t) * PK + k0 + sseg;
          *(ushort8v*)&As[row * LDA + sseg] = *(const ushort8v*)srcA;
        }
        const u16* srcB = W + (size_t)(nt0 + row) * PK + k0 + sseg;
        *(ushort8v*)&Bs[row * LDA + sseg] = *(const ushort8v*)srcB;
      }
      __syncthreads();
#pragma unroll
      for (int kk = 0; kk < BK; kk += 32) {
        bf16x8 af[4], bfr[2];
#pragma unroll
        for (int mt = 0; mt < 4; mt++)
          af[mt] = *(const bf16x8*)&As[(wr * 64 + mt * 16 + l15) * LDA + kk + q * 8];
#pragma unroll
        for (int nt = 0; nt < 2; nt++)
          bfr[nt] = *(const bf16x8*)&Bs[(wc * 32 + nt * 16 + l15) * LDA + kk + q * 8];
#pragma unroll
        for (int mt = 0; mt < 4; mt++)
#pragma unroll
          for (int nt = 0; nt < 2; nt++)
            acc[mt][nt] = __builtin_amdgcn_mfma_f32_16x16x32_bf16(af[mt], bfr[nt], acc[mt][nt], 0, 0, 0);
      }
    }

    const float* bih = dir ? bih1 : bih0;
    const float* bhh = dir ? bhh1 : bhh0;
    const float gsc = (gate == 2) ? L2E2 : L2E;
    // xpc dest for value (sl, row=b&7, gate, col):
    //   u16 off = sl*4096 + (col>>4)*512 + gate*128 + (col&15)*2
    //           + ((rb>>1)&1)*64 + ((rb>>2)&1)*32 + (rb&1)
    const int rb = b & 7;
    u16* xo = XPC + (size_t)(dir * 16 + (b >> 3)) * TC * 4096
                  + ((rb >> 1) & 1) * 64 + ((rb >> 2) & 1) * 32 + (rb & 1) + l15 * 2;
#pragma unroll
    for (int nt = 0; nt < 2; nt++) {
      int col = wc * 32 + nt * 16 + l15;          // within-gate col 0..127
      int n = nt0 + col;
      float bias = (bih[n] + bhh[n]) * gsc;
      int bnt = ((wc * 2 + nt) * 4 + gate) * 128;
#pragma unroll
      for (int mt = 0; mt < 4; mt++) {
        int slb = wr * 64 + mt * 16 + q * 4;   // step-local index base
#pragma unroll
        for (int r = 0; r < 4; r++)
          xo[(size_t)(slb + r) * 4096 + bnt] = f2bf(acc[mt][nt][r] + bias);
      }
    }
    return;
  }

  // -------------- lstm part (8 rows/WG, dup-READ reg-select remap) ---------
  if (!do_lstm) return;

  __builtin_amdgcn_s_setprio(3);

  const int wg = blockIdx.x & 15, dir = blockIdx.x >> 4;
  const int hc = 16 * wv + l15;
  const u16* XPC = (lc & 1) ? xpc1 : xpc0;

  // lane row ownership: rows {row0, row0+1}, col hc
  // q=0 -> {0,1}, q=1 -> {4,5}, q=2 -> {2,3}, q=3 -> {6,7}
  const int row0 = ((lane >> 4) & 1) * 4 + (lane >> 5) * 2;

  const u16* Wp = dir ? WHH1 : WHH0;
  bf16x8 wf[4][4];
#pragma unroll
  for (int gi = 0; gi < 4; gi++)
#pragma unroll
    for (int kt = 0; kt < 4; kt++)
      wf[gi][kt] = *(const bf16x8*)&Wp[(gi * 128 + hc) * 128 + kt * 32 + q * 8];

  u16* hb = (u16*)smem;   // [2][8*136] u16; A-rows 8..15 alias 0..7 via read addr

  const int g0 = (dir * 128 + wg * 8 + row0) * 128 + hc;  // HS/CS row0 slot
  f32x2 cst2;
  if (lc == 0) {
    for (int i = tid; i < 2 * 8 * 136; i += 512) hb[i] = 0;
    cst2 = (f32x2){0.f, 0.f};
  } else {
    // restore plane 0 rows 0..7 (each lane: its 2 rows at col hc)
    hb[row0 * 136 + hc] = HS[g0];
    hb[(row0 + 1) * 136 + hc] = HS[g0 + 128];
    cst2[0] = CS[g0];
    cst2[1] = CS[g0 + 128];
    // plane 1 needs no init: every step writes all 8 rows of the next plane
  }

  // xp lane base: one dword per gate per step at (colgrp=wv, gate, lane)
  const u16* xb = XPC + (size_t)(dir * 16 + wg) * TC * 4096 + wv * 512 + lane * 2;

#define LDXP(dst, s) do {                                        \
    const u16* nb_ = xb + (size_t)(s) * 4096;                    \
    _Pragma("unroll")                                            \
    for (int gi_ = 0; gi_ < 4; gi_++)                            \
      (dst)[gi_] = *(const unsigned int*)(nb_ + gi_ * 128);      \
  } while (0)

  // depth-3 prefetch: 4 rotating dword[4] buffers, static indexing
  unsigned int xp[4][4];
  LDXP(xp[0], 0);
  LDXP(xp[1], 1);
  LDXP(xp[2], 2);

  const int t0 = dir ? (NT - 1 - lc * TC) : (lc * TC);
  const int tstep = dir ? -256 : 256;
  u16* optr[2];
  if (LL == 0) {
#pragma unroll
    for (int rr = 0; rr < 2; rr++)
      optr[rr] = OUT + ((size_t)(wg * 8 + row0 + rr) * NT + t0) * 256 + dir * 128 + hc;
  }

  const f32x4 zero4 = {0.f, 0.f, 0.f, 0.f};
  const bool hi32 = (lane >= 32);
  const int arow = (l15 & 7) * 136;    // dup-read A-row address (rows mod 8)

  __syncthreads();

  int p = 0;
#pragma unroll 1
  for (int sl = 0; sl < TC; sl += 4) {
#pragma unroll
    for (int jj = 0; jj < 4; jj++) {
      const int scur = sl + jj;

      // ---- step top: consume xp (vmcnt wait lands HERE, loads 3 steps old)
      const unsigned int* xcur = xp[jj];
      f32x2 xv[4];
#pragma unroll
      for (int gi = 0; gi < 4; gi++) {
        union { unsigned int u; float f; } lo, hi;
        lo.u = xcur[gi] << 16;
        hi.u = xcur[gi] & 0xFFFF0000u;
        xv[gi][0] = lo.f; xv[gi][1] = hi.f;
      }
      // issue prefetch for step scur+3 (clamped; dead tail loads never read)
      {
        int sn = scur + 3; if (sn > TC - 1) sn = TC - 1;
        LDXP(xp[(jj + 3) & 3], sn);
      }

      // ---- A-fragment reads (rows mod 8: broadcast for upper half)
      bf16x8 ah[4];
#pragma unroll
      for (int kt = 0; kt < 4; kt++)
        ah[kt] = *(const bf16x8*)&hb[p * 1088 + arow + kt * 32 + q * 8];

      // MFMA with zero C-init (xp added after select)
      f32x4 acc[4];
#pragma unroll
      for (int gi = 0; gi < 4; gi++) {
        acc[gi] = __builtin_amdgcn_mfma_f32_16x16x32_bf16(ah[0], wf[gi][0], zero4, 0, 0, 0);
#pragma unroll
        for (int kt = 1; kt < 4; kt++)
          acc[gi] = __builtin_amdgcn_mfma_f32_16x16x32_bf16(ah[kt], wf[gi][kt], acc[gi], 0, 0, 0);
      }

      // dup remap: A rows 8..15 alias 0..7, so lane(l15,q) reg r = batch row
      // (4q+r) mod 8. row0={0,4,2,6}[q] -> regs {0,1} lanes<32, {2,3} lanes>=32.
      f32x2 ar[4];
#pragma unroll
      for (int gi = 0; gi < 4; gi++) {
        ar[gi][0] = hi32 ? acc[gi][2] : acc[gi][0];
        ar[gi][1] = hi32 ? acc[gi][3] : acc[gi][1];
      }

      // packed gate math (rr = vector lane). Preacts pre-scaled by L2E/L2E2.
      f32x2 pi = ar[0] + xv[0];
      f32x2 pf = ar[1] + xv[1];
      f32x2 pg = ar[2] + xv[2];
      f32x2 po = ar[3] + xv[3];
      f32x2 ei, ef, eg, eo;
      ei[0] = fast_exp2(pi[0]); ei[1] = fast_exp2(pi[1]);
      ef[0] = fast_exp2(pf[0]); ef[1] = fast_exp2(pf[1]);
      eg[0] = fast_exp2(pg[0]); eg[1] = fast_exp2(pg[1]);
      eo[0] = fast_exp2(po[0]); eo[1] = fast_exp2(po[1]);
      f32x2 A  = 1.f + ef;
      f32x2 Bv = 1.f + ei;
      f32x2 Cg = 1.f + eg;
      f32x2 BC = Bv * Cg;
      f32x2 num = cst2 * ef * BC + ei * (eg - 1.f) * A;
      f32x2 den = A * BC;
      f32x2 rden; rden[0] = fast_rcp(den[0]); rden[1] = fast_rcp(den[1]);
      f32x2 cn = num * rden;
      cst2 = cn;
      f32x2 tc2 = L2E2 * cn;
      f32x2 ec; ec[0] = fast_exp2(tc2[0]); ec[1] = fast_exp2(tc2[1]);
      f32x2 d2 = (1.f + eo) * (1.f + ec);
      f32x2 r2; r2[0] = fast_rcp(d2[0]); r2[1] = fast_rcp(d2[1]);
      f32x2 hv2 = eo * (ec - 1.f) * r2;

      u16 hbv0 = f2bf(hv2[0]);
      u16 hbv1 = f2bf(hv2[1]);
      u16* hn = hb + (p ^ 1) * 1088;
      hn[row0 * 136 + hc] = hbv0;
      hn[(row0 + 1) * 136 + hc] = hbv1;
      if (LL == 0) {
        *optr[0] = hbv0; optr[0] += tstep;
        *optr[1] = hbv1; optr[1] += tstep;
      }
      if (scur == TC - 1) {
        HS[g0] = hbv0;
        HS[g0 + 128] = hbv1;
        CS[g0] = cst2[0];
        CS[g0 + 128] = cst2[1];
        if (LL == 1 && lc == NCHUNK - 1) {
          FINALS[(wg * 8 + row0) * 256 + dir * 128 + hc] = hv2[0];
          FINALS[(wg * 8 + row0 + 1) * 256 + dir * 128 + hc] = hv2[1];
        }
      }
      sync_lds();   // h-exchange: lgkmcnt(0)+barrier; VMEM stays in flight
      p ^= 1;
    }
  }
#undef LDXP
}

// ---------------------------------------------------------------------------
// fc: out[b][c] = finals[b][:] . fc_w[c][:] + fc_b[c]  (all f32)
__global__ void fc_kernel(const float* __restrict__ finals, const float* __restrict__ fcw,
                          const float* __restrict__ fcb, float* __restrict__ out) {
  int tid = threadIdx.x;  // 256 = 128 b x 2 c
  int b = tid >> 1, cc = tid & 1;
  float s = fcb[cc];
  for (int k = 0; k < 256; k++) s += finals[b * 256 + k] * fcw[cc * 256 + k];
  out[b * 2 + cc] = s;
}

// ---------------------------------------------------------------------------
extern "C" void kernel_launch(void* const* d_in, const int* in_sizes, int n_in,
                              void* d_out, int out_size, void* d_ws, size_t ws_size,
                              hipStream_t stream) {
  const int*   x        = (const int*)d_in[0];
  const float* emb      = (const float*)d_in[1];
  const float* w_ih_l0  = (const float*)d_in[2];
  const float* w_hh_l0  = (const float*)d_in[3];
  const float* b_ih_l0  = (const float*)d_in[4];
  const float* b_hh_l0  = (const float*)d_in[5];
  const float* w_ih_l0r = (const float*)d_in[6];
  const float* w_hh_l0r = (const float*)d_in[7];
  const float* b_ih_l0r = (const float*)d_in[8];
  const float* b_hh_l0r = (const float*)d_in[9];
  const float* w_ih_l1  = (const float*)d_in[10];
  const float* w_hh_l1  = (const float*)d_in[11];
  const float* b_ih_l1  = (const float*)d_in[12];
  const float* b_hh_l1  = (const float*)d_in[13];
  const float* w_ih_l1r = (const float*)d_in[14];
  const float* w_hh_l1r = (const float*)d_in[15];
  const float* b_ih_l1r = (const float*)d_in[16];
  const float* b_hh_l1r = (const float*)d_in[17];
  const float* fc_w     = (const float*)d_in[18];
  const float* fc_b     = (const float*)d_in[19];
  float* out = (float*)d_out;

  // workspace layout — total 135,856,128 B (r8-r21 footprint, proven)
  char* ws = (char*)d_ws;
  size_t off = 0;
  u16*   h1cat = (u16*)(ws + off);   off += 67108864;  // [NB*NT][256] bf16
  u16*   xpc0  = (u16*)(ws + off);   off += 33554432;  // xp double buffer 0
  u16*   xpc1  = (u16*)(ws + off);   off += 33554432;  // xp double buffer 1
  u16*   w0pad = (u16*)(ws + off);   off += 262144;    // [2][512][128] bf16 (scaled)
  u16*   wih1b = (u16*)(ws + off);   off += 524288;    // [2][512][256] bf16 (scaled)
  u16*   whhb  = (u16*)(ws + off);   off += 524288;    // [4][512][128] bf16 (scaled)
  u16*   hs    = (u16*)(ws + off);   off += 65536;     // [2][128][128] bf16
  float* cs    = (float*)(ws + off); off += 131072;    // [2][128][128] f32
  float* fin   = (float*)(ws + off); off += 131072;    // [128][256] f32
  if (ws_size < off) return;  // constant across calls -> same work every call

  hipLaunchKernelGGL(padw_kernel, dim3(512), dim3(256), 0, stream,
                     w_ih_l0, w_ih_l0r, w0pad);
  hipLaunchKernelGGL(cvt6_kernel, dim3(512, 6), dim3(256), 0, stream,
                     w_hh_l0, w_hh_l0r, w_hh_l1, w_hh_l1r, w_ih_l1, w_ih_l1r,
                     whhb, whhb + 65536, whhb + 131072, whhb + 196608,
                     wih1b, wih1b + 131072,
                     65536, 65536, 65536, 65536, 131072, 131072);

  // Layer 0: launch k does proj0(k) [k<8] fused with lstm0(k-1) [k>0]
  for (int k = 0; k <= NCHUNK; k++) {
    int do_proj = (k < NCHUNK);
    int do_lstm = (k > 0);
    hipLaunchKernelGGL((fused_chunk<128, 0>), dim3(do_proj ? 1056 : 32), dim3(512),
                       SMEM_BYTES, stream,
                       do_lstm, k - 1, k,
                       emb, (const u16*)nullptr, x, w0pad, w0pad + 65536,
                       b_ih_l0, b_hh_l0, b_ih_l0r, b_hh_l0r,
                       xpc0, xpc1, whhb, whhb + 65536,
                       h1cat, fin, hs, cs);
  }
  // Layer 1: same pattern, proj reads h1cat (complete after layer-0 phase)
  for (int k = 0; k <= NCHUNK; k++) {
    int do_proj = (k < NCHUNK);
    int do_lstm = (k > 0);
    hipLaunchKernelGGL((fused_chunk<256, 1>), dim3(do_proj ? 1056 : 32), dim3(512),
                       SMEM_BYTES, stream,
                       do_lstm, k - 1, k,
                       (const float*)nullptr, h1cat, (const int*)nullptr,
                       wih1b, wih1b + 131072,
                       b_ih_l1, b_hh_l1, b_ih_l1r, b_hh_l1r,
                       xpc0, xpc1, whhb + 131072, whhb + 196608,
                       h1cat, fin, hs, cs);
  }
  hipLaunchKernelGGL(fc_kernel, dim3(1), dim3(256), 0, stream, fin, fc_w, fc_b, out);
}